// Round 3
// baseline (1523.634 us; speedup 1.0000x reference)
//
#include <hip/hip_runtime.h>
#include <hip/hip_bf16.h>
#include <stdint.h>

#define N_ATOMS 40000
#define N_BONDS 90000
#define MAX_NB 6
#define ATOM_FDIM 133
#define BOND_FDIM 147
#define HIDDEN 300
#define DEPTH 6

// padded dims
#define KB_PAD 160      // bond fdim 147 -> 160 (5 ksteps of 32)
#define KA_PAD 160      // atom fdim 133 -> 160
#define HP 320          // hidden 300 -> 320 (10 ksteps of 32)
#define NB_PAD 90112    // bonds padded to mult of 128
#define NA_PAD 40064    // atoms padded to mult of 128

typedef unsigned short u16;
typedef unsigned int uint32;

typedef __bf16 bf16x8 __attribute__((ext_vector_type(8)));
typedef float f32x4 __attribute__((ext_vector_type(4)));

#define GLOBAL_AS __attribute__((address_space(1)))
#define LDS_AS __attribute__((address_space(3)))

__device__ __forceinline__ void async_copy16(const void* g, void* l) {
    __builtin_amdgcn_global_load_lds((GLOBAL_AS void*)(void*)g,
                                     (LDS_AS void*)l, 16, 0, 0);
}

__device__ __forceinline__ float bf2f(u16 s) {
    union { uint32 u; float f; } v; v.u = ((uint32)s) << 16; return v.f;
}
__device__ __forceinline__ u16 f2bf(float f) {
    union { float f; uint32 u; } v; v.f = f;
    uint32 r = v.u + 0x7fffu + ((v.u >> 16) & 1u);
    return (u16)(r >> 16);
}
__device__ __forceinline__ float sigm(float x) { return 1.f / (1.f + __expf(-x)); }
__device__ __forceinline__ float tanh_s(float x) {
    float e = __expf(-2.f * fabsf(x));
    float t = (1.f - e) / (1.f + e);
    return x >= 0.f ? t : -t;
}

// --- XOR chunk swizzle: within each 64B group (4 chunks of 16B), physical
// chunk = logical chunk ^ ((row>>1)&3). Makes wave64 b128 LDS frag reads
// bank-conflict-free while keeping global_load_lds staging contiguous.
__device__ __forceinline__ int swz_chunk(int c, int row) {
    return (c & ~3) | ((c & 3) ^ ((row >> 1) & 3));
}
__device__ __forceinline__ int swz_elem(int e, int row) {
    return (e & ~31) | (((((e >> 3) & 3)) ^ ((row >> 1) & 3)) << 3) | (e & 7);
}

// ---------------------------------------------------------------------------
// Generic GEMM: C_g[M x 320] = A[M x K] @ B_g[320 x K]^T, bf16, fp32 acc.
// All bf16 operand buffers are pre-swizzled (swz_elem by row).
// Tile 128 x 64 per block, 4 waves. A2/ksplit: K-concat second A source.
// EPI 0: bf16 store (+bias) to C1 (swizzled). EPI 2: bias+relu+mask fp32 out.
// ---------------------------------------------------------------------------
template<int NG, int EPI>
__global__ __launch_bounds__(256, 2) void gemm_k(
    const u16* __restrict__ A, int ldaB,
    const u16* __restrict__ A2, int lda2B, int ksplit,
    const u16* __restrict__ Bw, int ldbB,
    int ksteps, int M,
    u16* __restrict__ C1, int ldc,
    const float* __restrict__ bias,
    float* __restrict__ outp, const float* __restrict__ omask)
{
    __shared__ __align__(16) u16 lsA[128 * 32];
    __shared__ __align__(16) u16 lsB[NG * 64 * 32];

    const int tid = threadIdx.x;
    const int wv = tid >> 6, ln = tid & 63;
    const int m0 = blockIdx.x * 128;
    const int n0 = blockIdx.y * 64;
    const int lhalf = ln >> 4, l16 = ln & 15;
    const int aoff = ((lhalf ^ ((l16 >> 1) & 3))) * 8;  // swizzled k-chunk per lane

    f32x4 acc[NG][2][4];
#pragma unroll
    for (int g = 0; g < NG; ++g)
#pragma unroll
        for (int r = 0; r < 2; ++r)
#pragma unroll
            for (int c = 0; c < 4; ++c) { f32x4 z = {0.f, 0.f, 0.f, 0.f}; acc[g][r][c] = z; }

    for (int ks = 0; ks < ksteps; ++ks) {
        __syncthreads();
        const char* Abase; int ldA;
        if (ks < ksplit) { Abase = (const char*)A + (size_t)ks * 64; ldA = ldaB; }
        else             { Abase = (const char*)A2 + (size_t)(ks - ksplit) * 64; ldA = lda2B; }
#pragma unroll
        for (int c = 0; c < 2; ++c) {
            int chunk = wv * 2 + c;
            int idx = chunk * 64 + ln;
            int row = idx >> 2, kb = (idx & 3) * 16;
            async_copy16(Abase + (size_t)(m0 + row) * ldA + kb, &lsA[chunk * 512]);
        }
#pragma unroll
        for (int g = 0; g < NG; ++g) {
            int idx = wv * 64 + ln;
            int n = idx >> 2, kb = (idx & 3) * 16;
            async_copy16((const char*)Bw + (size_t)(g * 320 + n0 + n) * ldbB + (size_t)ks * 64 + kb,
                         &lsB[g * 2048 + wv * 512]);
        }
        __syncthreads();

        bf16x8 af[2];
#pragma unroll
        for (int r = 0; r < 2; ++r)
            af[r] = *(const bf16x8*)&lsA[(wv * 32 + r * 16 + l16) * 32 + aoff];
#pragma unroll
        for (int g = 0; g < NG; ++g) {
#pragma unroll
            for (int c = 0; c < 4; ++c) {
                bf16x8 bfv = *(const bf16x8*)&lsB[g * 2048 + (c * 16 + l16) * 32 + aoff];
#pragma unroll
                for (int r = 0; r < 2; ++r)
                    acc[g][r][c] = __builtin_amdgcn_mfma_f32_16x16x32_bf16(af[r], bfv, acc[g][r][c], 0, 0, 0);
            }
        }
    }

    const int mrow_base = m0 + wv * 32;
#pragma unroll
    for (int r = 0; r < 2; ++r) {
#pragma unroll
        for (int c = 0; c < 4; ++c) {
            int nn_ = n0 + c * 16 + l16;
#pragma unroll
            for (int i = 0; i < 4; ++i) {
                int m = mrow_base + r * 16 + lhalf * 4 + i;
                if (m >= M) continue;
                if constexpr (EPI == 0) {
                    int pc = swz_elem(nn_, m);
#pragma unroll
                    for (int g = 0; g < NG; ++g) {
                        float v = acc[g][r][c][i];
                        if (bias != nullptr && nn_ < HIDDEN) v += bias[g * HIDDEN + nn_];
                        C1[(size_t)m * ldc + g * 320 + pc] = f2bf(v);
                    }
                } else { // EPI == 2
                    if (nn_ < HIDDEN) {
                        float v = acc[0][r][c][i] + (bias ? bias[nn_] : 0.f);
                        v = fmaxf(v, 0.f);
                        if (omask) v *= omask[m];
                        outp[(size_t)m * HIDDEN + nn_] = v;
                    }
                }
            }
        }
    }
}

// ---------------------------------------------------------------------------
// Fused GRU GEMM: A = [fb (K 0..159) | h (K 160..479)], 4 gates.
// Gate 0 (r), 1 (z): full K. Gate 2 (i_n): fb half only. Gate 3 (h_n): h half
// only. Zero blocks are skipped (bit-exact). Epilogue applies GRU nonlinearity.
// ---------------------------------------------------------------------------
__global__ __launch_bounds__(256, 2) void gemm_gru_k(
    const u16* __restrict__ A1,   // fb_p [NB_PAD][160] swizzled
    const u16* __restrict__ A2,   // hbuf [NB_PAD][320] swizzled
    const u16* __restrict__ Bw,   // W4 [4][320][480] swizzled
    const float* __restrict__ bias,  // [4*320]
    const u16* __restrict__ hbuf,
    u16* __restrict__ msg_out)
{
    __shared__ __align__(16) u16 lsA[128 * 32];
    __shared__ __align__(16) u16 lsB[4 * 64 * 32];

    const int tid = threadIdx.x;
    const int wv = tid >> 6, ln = tid & 63;
    const int m0 = blockIdx.x * 128;
    const int n0 = blockIdx.y * 64;
    const int lhalf = ln >> 4, l16 = ln & 15;
    const int aoff = ((lhalf ^ ((l16 >> 1) & 3))) * 8;

    f32x4 acc[4][2][4];
#pragma unroll
    for (int g = 0; g < 4; ++g)
#pragma unroll
        for (int r = 0; r < 2; ++r)
#pragma unroll
            for (int c = 0; c < 4; ++c) { f32x4 z = {0.f, 0.f, 0.f, 0.f}; acc[g][r][c] = z; }

    for (int ks = 0; ks < 15; ++ks) {
        const int ph0 = (ks < 5);
        const int g2sel = ph0 ? 2 : 3;
        __syncthreads();
        const char* Abase = ph0 ? ((const char*)A1 + (size_t)ks * 64)
                                : ((const char*)A2 + (size_t)(ks - 5) * 64);
        const int ldA = ph0 ? (KB_PAD * 2) : (HP * 2);
#pragma unroll
        for (int c = 0; c < 2; ++c) {
            int chunk = wv * 2 + c;
            int idx = chunk * 64 + ln;
            int row = idx >> 2, kb = (idx & 3) * 16;
            async_copy16(Abase + (size_t)(m0 + row) * ldA + kb, &lsA[chunk * 512]);
        }
#pragma unroll
        for (int gi = 0; gi < 3; ++gi) {
            int g = (gi < 2) ? gi : g2sel;
            int idx = wv * 64 + ln;
            int n = idx >> 2, kb = (idx & 3) * 16;
            async_copy16((const char*)Bw + (size_t)(g * 320 + n0 + n) * 960 + (size_t)ks * 64 + kb,
                         &lsB[g * 2048 + wv * 512]);
        }
        __syncthreads();

        bf16x8 af[2];
#pragma unroll
        for (int r = 0; r < 2; ++r)
            af[r] = *(const bf16x8*)&lsA[(wv * 32 + r * 16 + l16) * 32 + aoff];
#pragma unroll
        for (int gi = 0; gi < 3; ++gi) {
            int g = (gi < 2) ? gi : g2sel;
#pragma unroll
            for (int c = 0; c < 4; ++c) {
                bf16x8 bfv = *(const bf16x8*)&lsB[g * 2048 + (c * 16 + l16) * 32 + aoff];
#pragma unroll
                for (int r = 0; r < 2; ++r)
                    acc[g][r][c] = __builtin_amdgcn_mfma_f32_16x16x32_bf16(af[r], bfv, acc[g][r][c], 0, 0, 0);
            }
        }
    }

    const int mrow_base = m0 + wv * 32;
#pragma unroll
    for (int r = 0; r < 2; ++r) {
#pragma unroll
        for (int c = 0; c < 4; ++c) {
            int nn_ = n0 + c * 16 + l16;
#pragma unroll
            for (int i = 0; i < 4; ++i) {
                int m = mrow_base + r * 16 + lhalf * 4 + i;
                if (m >= N_BONDS) continue;
                int pc = swz_elem(nn_, m);
                float rl  = acc[0][r][c][i] + bias[nn_];
                float zl  = acc[1][r][c][i] + bias[320 + nn_];
                float in_ = acc[2][r][c][i] + bias[640 + nn_];
                float hn_ = acc[3][r][c][i] + bias[960 + nn_];
                float hv = bf2f(hbuf[(size_t)m * HP + pc]);
                float rr = sigm(rl);
                float zz = sigm(zl);
                float nv = tanh_s(in_ + rr * hn_);
                float msg = (1.f - zz) * nv + zz * hv;
                if (m == 0) msg = 0.f;
                msg_out[(size_t)m * HP + pc] = f2bf(msg);
            }
        }
    }
}

// a_message[a,:] = sum_j message[a2b[a,j],:]  (bf16, swizzled rows both sides)
__global__ __launch_bounds__(256) void gather_sum_k(
    const u16* __restrict__ msg, const int* __restrict__ a2b, u16* __restrict__ amsg)
{
    int u = blockIdx.x * 256 + threadIdx.x;
    if (u >= N_ATOMS * 40) return;
    int a = u / 40, c = u - a * 40;
    const uint4* mp = (const uint4*)msg;
    float s[8];
#pragma unroll
    for (int t = 0; t < 8; ++t) s[t] = 0.f;
#pragma unroll
    for (int j = 0; j < MAX_NB; ++j) {
        int b = a2b[a * MAX_NB + j];
        uint4 v = mp[(size_t)b * 40 + swz_chunk(c, b)];
        s[0] += bf2f((u16)(v.x & 0xffff)); s[1] += bf2f((u16)(v.x >> 16));
        s[2] += bf2f((u16)(v.y & 0xffff)); s[3] += bf2f((u16)(v.y >> 16));
        s[4] += bf2f((u16)(v.z & 0xffff)); s[5] += bf2f((u16)(v.z >> 16));
        s[6] += bf2f((u16)(v.w & 0xffff)); s[7] += bf2f((u16)(v.w >> 16));
    }
    uint4 o;
    o.x = (uint32)f2bf(s[0]) | ((uint32)f2bf(s[1]) << 16);
    o.y = (uint32)f2bf(s[2]) | ((uint32)f2bf(s[3]) << 16);
    o.z = (uint32)f2bf(s[4]) | ((uint32)f2bf(s[5]) << 16);
    o.w = (uint32)f2bf(s[6]) | ((uint32)f2bf(s[7]) << 16);
    ((uint4*)amsg)[(size_t)a * 40 + swz_chunk(c, a)] = o;
}

// h[b,:] = amsg[b2a[b],:] - msg[b2revb[b],:]  (swizzled rows everywhere)
__global__ __launch_bounds__(256) void build_h_k(
    const u16* __restrict__ amsg, const u16* __restrict__ msg,
    const int* __restrict__ b2a, const int* __restrict__ b2revb, u16* __restrict__ h)
{
    int u = blockIdx.x * 256 + threadIdx.x;
    if (u >= N_BONDS * 40) return;
    int b = u / 40, c = u - b * 40;
    int ra = b2a[b], rm = b2revb[b];
    uint4 va = ((const uint4*)amsg)[(size_t)ra * 40 + swz_chunk(c, ra)];
    uint4 vm = ((const uint4*)msg)[(size_t)rm * 40 + swz_chunk(c, rm)];
    uint4 o;
    o.x = (uint32)f2bf(bf2f((u16)(va.x & 0xffff)) - bf2f((u16)(vm.x & 0xffff)))
        | ((uint32)f2bf(bf2f((u16)(va.x >> 16)) - bf2f((u16)(vm.x >> 16))) << 16);
    o.y = (uint32)f2bf(bf2f((u16)(va.y & 0xffff)) - bf2f((u16)(vm.y & 0xffff)))
        | ((uint32)f2bf(bf2f((u16)(va.y >> 16)) - bf2f((u16)(vm.y >> 16))) << 16);
    o.z = (uint32)f2bf(bf2f((u16)(va.z & 0xffff)) - bf2f((u16)(vm.z & 0xffff)))
        | ((uint32)f2bf(bf2f((u16)(va.z >> 16)) - bf2f((u16)(vm.z >> 16))) << 16);
    o.w = (uint32)f2bf(bf2f((u16)(va.w & 0xffff)) - bf2f((u16)(vm.w & 0xffff)))
        | ((uint32)f2bf(bf2f((u16)(va.w >> 16)) - bf2f((u16)(vm.w >> 16))) << 16);
    ((uint4*)h)[(size_t)b * 40 + swz_chunk(c, b)] = o;
}

// pad+cast fp32 -> bf16, swizzled destination
__global__ __launch_bounds__(256) void padcast_k(
    const float* __restrict__ src, int srows, int scols,
    u16* __restrict__ dst, int drows, int dcols)
{
    int idx = blockIdx.x * 256 + threadIdx.x;
    if (idx >= drows * dcols) return;
    int r = idx / dcols, c = idx - r * dcols;
    float v = (r < srows && c < scols) ? src[(size_t)r * scols + c] : 0.f;
    dst[(size_t)r * dcols + swz_elem(c, r)] = f2bf(v);
}

// Wf[900][160] fp32 = W_ih[900][300] @ W_i[300][147] (cols >=147 zero), unswizzled
__global__ __launch_bounds__(256) void wf_k(
    const float* __restrict__ W_ih, const float* __restrict__ W_i, float* __restrict__ Wf)
{
    int idx = blockIdx.x * 256 + threadIdx.x;
    if (idx >= 900 * 160) return;
    int r = idx / 160, c = idx - r * 160;
    float s = 0.f;
    if (c < BOND_FDIM) {
        for (int k = 0; k < HIDDEN; ++k)
            s += W_ih[(size_t)r * HIDDEN + k] * W_i[(size_t)k * BOND_FDIM + c];
    }
    Wf[idx] = s;
}

// W4[4][320][480] bf16 swizzled: r/z: [Wf_g | W_hh_g]; i_n: [Wf_n | 0]; h_n: [0 | W_hh_n]
__global__ __launch_bounds__(256) void prep_W4_k(
    const float* __restrict__ Wf, const float* __restrict__ W_hh, u16* __restrict__ W4)
{
    int idx = blockIdx.x * 256 + threadIdx.x;
    if (idx >= 4 * HP * 480) return;
    int g = idx / (HP * 480); int rem = idx - g * HP * 480;
    int n = rem / 480, k = rem - n * 480;
    float v = 0.f;
    if (n < HIDDEN) {
        if (g <= 1) {
            if (k < KB_PAD) v = Wf[(size_t)(g * HIDDEN + n) * 160 + k];
            else if (k < KB_PAD + HIDDEN) v = W_hh[(size_t)(g * HIDDEN + n) * HIDDEN + (k - KB_PAD)];
        } else if (g == 2) {
            if (k < KB_PAD) v = Wf[(size_t)(2 * HIDDEN + n) * 160 + k];
        } else {
            if (k >= KB_PAD && k < KB_PAD + HIDDEN) v = W_hh[(size_t)(2 * HIDDEN + n) * HIDDEN + (k - KB_PAD)];
        }
    }
    W4[(size_t)(g * HP + n) * 480 + swz_elem(k, n)] = f2bf(v);
}

// bias4[4*320]: r: b_ih_r+b_hh_r; z: b_ih_z+b_hh_z; i_n: b_ih_n; h_n: b_hh_n
__global__ __launch_bounds__(256) void bias4_k(
    const float* __restrict__ b_ih, const float* __restrict__ b_hh, float* __restrict__ b4)
{
    int idx = blockIdx.x * 256 + threadIdx.x;
    if (idx >= 4 * HP) return;
    int g = idx / HP, n = idx - g * HP;
    float v = 0.f;
    if (n < HIDDEN) {
        if (g == 0) v = b_ih[n] + b_hh[n];
        else if (g == 1) v = b_ih[HIDDEN + n] + b_hh[HIDDEN + n];
        else if (g == 2) v = b_ih[2 * HIDDEN + n];
        else v = b_hh[2 * HIDDEN + n];
    }
    b4[idx] = v;
}

// W_o [300][433] -> [320][480] swizzled: k<133 atom part, k in [160,460) hidden part
__global__ __launch_bounds__(256) void padWo_k(const float* __restrict__ src, u16* __restrict__ dst)
{
    int idx = blockIdx.x * 256 + threadIdx.x;
    if (idx >= HP * 480) return;
    int n = idx / 480, k = idx - n * 480;
    float v = 0.f;
    if (n < HIDDEN) {
        if (k < ATOM_FDIM) v = src[(size_t)n * 433 + k];
        else if (k >= KA_PAD && k < KA_PAD + HIDDEN) v = src[(size_t)n * 433 + ATOM_FDIM + (k - KA_PAD)];
    }
    dst[(size_t)n * 480 + swz_elem(k, n)] = f2bf(v);
}

__global__ __launch_bounds__(256) void sentinel_k(float* __restrict__ out, int n)
{
    int i = blockIdx.x * 256 + threadIdx.x;
    if (i < n) out[i] = 31415.0f;
}

extern "C" void kernel_launch(void* const* d_in, const int* in_sizes, int n_in,
                              void* d_out, int out_size, void* d_ws, size_t ws_size,
                              hipStream_t stream)
{
    const float* f_atoms = (const float*)d_in[0];
    const float* f_bonds = (const float*)d_in[1];
    const int*   a2b     = (const int*)d_in[2];
    const int*   b2a     = (const int*)d_in[3];
    const int*   b2revb  = (const int*)d_in[4];
    const float* maskp   = (const float*)d_in[8];
    const float* W_i     = (const float*)d_in[9];
    const float* W_ih    = (const float*)d_in[10];
    const float* W_hh    = (const float*)d_in[11];
    const float* b_ih    = (const float*)d_in[12];
    const float* b_hh    = (const float*)d_in[13];
    const float* W_o_w   = (const float*)d_in[14];
    const float* W_o_b   = (const float*)d_in[15];
    float* out = (float*)d_out;

    char* ws = (char*)d_ws;
    size_t off = 0;
    auto alloc = [&](size_t bytes) -> char* {
        char* p = ws + off;
        off += (bytes + 255) & ~(size_t)255;
        return p;
    };
    u16*   Wi_p   = (u16*)alloc((size_t)HP * KB_PAD * 2);
    u16*   W4     = (u16*)alloc((size_t)4 * HP * 480 * 2);
    u16*   Wo_p   = (u16*)alloc((size_t)HP * 480 * 2);
    float* bias4  = (float*)alloc((size_t)4 * HP * 4);
    float* Wf     = (float*)alloc((size_t)900 * 160 * 4);
    u16*   fa_p   = (u16*)alloc((size_t)NA_PAD * KA_PAD * 2);
    u16*   fb_p   = (u16*)alloc((size_t)NB_PAD * KB_PAD * 2);
    u16*   message= (u16*)alloc((size_t)NB_PAD * HP * 2);
    u16*   hbuf   = (u16*)alloc((size_t)NB_PAD * HP * 2);
    u16*   amsg   = (u16*)alloc((size_t)NA_PAD * HP * 2);

    if (off > ws_size) {
        sentinel_k<<<(out_size + 255) / 256, 256, 0, stream>>>(out, out_size);
        return;
    }

    // --- prep (all bf16 buffers written pre-swizzled) ---
    padcast_k<<<(HP * KB_PAD + 255) / 256, 256, 0, stream>>>(W_i, HIDDEN, BOND_FDIM, Wi_p, HP, KB_PAD);
    padcast_k<<<(NB_PAD * KB_PAD + 255) / 256, 256, 0, stream>>>(f_bonds, N_BONDS, BOND_FDIM, fb_p, NB_PAD, KB_PAD);
    padcast_k<<<(NA_PAD * KA_PAD + 255) / 256, 256, 0, stream>>>(f_atoms, N_ATOMS, ATOM_FDIM, fa_p, NA_PAD, KA_PAD);
    wf_k<<<(900 * 160 + 255) / 256, 256, 0, stream>>>(W_ih, W_i, Wf);
    prep_W4_k<<<(4 * HP * 480 + 255) / 256, 256, 0, stream>>>(Wf, W_hh, W4);
    bias4_k<<<(4 * HP + 255) / 256, 256, 0, stream>>>(b_ih, b_hh, bias4);
    padWo_k<<<(HP * 480 + 255) / 256, 256, 0, stream>>>(W_o_w, Wo_p);

    dim3 blk(256);
    dim3 gB(NB_PAD / 128, 5);
    // message = inp = f_bonds @ W_i.T
    gemm_k<1, 0><<<gB, blk, 0, stream>>>(fb_p, KB_PAD * 2, nullptr, 0, 1 << 30, Wi_p, KB_PAD * 2,
                                         5, N_BONDS, message, HP,
                                         nullptr, nullptr, nullptr);
    for (int d = 0; d < DEPTH - 1; ++d) {
        gather_sum_k<<<(N_ATOMS * 40 + 255) / 256, 256, 0, stream>>>(message, a2b, amsg);
        build_h_k<<<(N_BONDS * 40 + 255) / 256, 256, 0, stream>>>(amsg, message, b2a, b2revb, hbuf);
        gemm_gru_k<<<gB, blk, 0, stream>>>(fb_p, hbuf, W4, bias4, hbuf, message);
    }
    gather_sum_k<<<(N_ATOMS * 40 + 255) / 256, 256, 0, stream>>>(message, a2b, amsg);
    dim3 gO(NA_PAD / 128, 5);
    gemm_k<1, 2><<<gO, blk, 0, stream>>>(fa_p, KA_PAD * 2, amsg, HP * 2, 5, Wo_p, 480 * 2,
                                         15, N_ATOMS, nullptr, 0,
                                         W_o_b, out, maskp);
}

// Round 4
// 1505.967 us; speedup vs baseline: 1.0117x; 1.0117x over previous
//
#include <hip/hip_runtime.h>
#include <hip/hip_bf16.h>
#include <stdint.h>

#define N_ATOMS 40000
#define N_BONDS 90000
#define MAX_NB 6
#define ATOM_FDIM 133
#define BOND_FDIM 147
#define HIDDEN 300
#define DEPTH 6

// padded dims
#define KB_PAD 160      // bond fdim 147 -> 160 (5 ksteps of 32)
#define KA_PAD 160      // atom fdim 133 -> 160
#define HP 320          // hidden 300 -> 320 (10 ksteps of 32)
#define NB_PAD 90112    // bonds padded to mult of 128
#define NA_PAD 40064    // atoms padded to mult of 128

typedef unsigned short u16;
typedef unsigned int uint32;

typedef __bf16 bf16x8 __attribute__((ext_vector_type(8)));
typedef float f32x4 __attribute__((ext_vector_type(4)));

#define GLOBAL_AS __attribute__((address_space(1)))
#define LDS_AS __attribute__((address_space(3)))

__device__ __forceinline__ void async_copy16(const void* g, void* l) {
    __builtin_amdgcn_global_load_lds((GLOBAL_AS void*)(void*)g,
                                     (LDS_AS void*)l, 16, 0, 0);
}

__device__ __forceinline__ float bf2f(u16 s) {
    union { uint32 u; float f; } v; v.u = ((uint32)s) << 16; return v.f;
}
__device__ __forceinline__ u16 f2bf(float f) {
    union { float f; uint32 u; } v; v.f = f;
    uint32 r = v.u + 0x7fffu + ((v.u >> 16) & 1u);
    return (u16)(r >> 16);
}
__device__ __forceinline__ float sigm(float x) { return 1.f / (1.f + __expf(-x)); }
__device__ __forceinline__ float tanh_s(float x) {
    float e = __expf(-2.f * fabsf(x));
    float t = (1.f - e) / (1.f + e);
    return x >= 0.f ? t : -t;
}

// --- XOR chunk swizzle: within each 64B group (4 chunks of 16B), physical
// chunk = logical chunk ^ ((row>>1)&3). Conflict-free wave64 b128 LDS frag
// reads while keeping global_load_lds staging contiguous. (R3: verified
// SQ_LDS_BANK_CONFLICT == 0 with this layout.)
__device__ __forceinline__ int swz_chunk(int c, int row) {
    return (c & ~3) | ((c & 3) ^ ((row >> 1) & 3));
}
__device__ __forceinline__ int swz_elem(int e, int row) {
    return (e & ~31) | (((((e >> 3) & 3)) ^ ((row >> 1) & 3)) << 3) | (e & 7);
}

// ---------------------------------------------------------------------------
// Generic GEMM: C_g[M x 320] = A[M x K] @ B_g[320 x K]^T, bf16, fp32 acc.
// All bf16 operand buffers pre-swizzled (swz_elem by row).
// Tile 128 x 64 per block, 4 waves. A2/ksplit: K-concat second A source.
// EPI 0: bf16 store (+bias) to C1 (swizzled). EPI 2: bias+relu+mask fp32 out.
// ---------------------------------------------------------------------------
template<int NG, int EPI>
__global__ __launch_bounds__(256, 2) void gemm_k(
    const u16* __restrict__ A, int ldaB,
    const u16* __restrict__ A2, int lda2B, int ksplit,
    const u16* __restrict__ Bw, int ldbB,
    int ksteps, int M,
    u16* __restrict__ C1, int ldc,
    const float* __restrict__ bias,
    float* __restrict__ outp, const float* __restrict__ omask)
{
    __shared__ __align__(16) u16 lsA[128 * 32];
    __shared__ __align__(16) u16 lsB[NG * 64 * 32];

    const int tid = threadIdx.x;
    const int wv = tid >> 6, ln = tid & 63;
    const int m0 = blockIdx.x * 128;
    const int n0 = blockIdx.y * 64;
    const int lhalf = ln >> 4, l16 = ln & 15;
    const int aoff = ((lhalf ^ ((l16 >> 1) & 3))) * 8;

    f32x4 acc[NG][2][4];
#pragma unroll
    for (int g = 0; g < NG; ++g)
#pragma unroll
        for (int r = 0; r < 2; ++r)
#pragma unroll
            for (int c = 0; c < 4; ++c) { f32x4 z = {0.f, 0.f, 0.f, 0.f}; acc[g][r][c] = z; }

    for (int ks = 0; ks < ksteps; ++ks) {
        __syncthreads();
        const char* Abase; int ldA;
        if (ks < ksplit) { Abase = (const char*)A + (size_t)ks * 64; ldA = ldaB; }
        else             { Abase = (const char*)A2 + (size_t)(ks - ksplit) * 64; ldA = lda2B; }
#pragma unroll
        for (int c = 0; c < 2; ++c) {
            int chunk = wv * 2 + c;
            int idx = chunk * 64 + ln;
            int row = idx >> 2, kb = (idx & 3) * 16;
            async_copy16(Abase + (size_t)(m0 + row) * ldA + kb, &lsA[chunk * 512]);
        }
#pragma unroll
        for (int g = 0; g < NG; ++g) {
            int idx = wv * 64 + ln;
            int n = idx >> 2, kb = (idx & 3) * 16;
            async_copy16((const char*)Bw + (size_t)(g * 320 + n0 + n) * ldbB + (size_t)ks * 64 + kb,
                         &lsB[g * 2048 + wv * 512]);
        }
        __syncthreads();

        bf16x8 af[2];
#pragma unroll
        for (int r = 0; r < 2; ++r)
            af[r] = *(const bf16x8*)&lsA[(wv * 32 + r * 16 + l16) * 32 + aoff];
#pragma unroll
        for (int g = 0; g < NG; ++g) {
#pragma unroll
            for (int c = 0; c < 4; ++c) {
                bf16x8 bfv = *(const bf16x8*)&lsB[g * 2048 + (c * 16 + l16) * 32 + aoff];
#pragma unroll
                for (int r = 0; r < 2; ++r)
                    acc[g][r][c] = __builtin_amdgcn_mfma_f32_16x16x32_bf16(af[r], bfv, acc[g][r][c], 0, 0, 0);
            }
        }
    }

    const int mrow_base = m0 + wv * 32;
#pragma unroll
    for (int r = 0; r < 2; ++r) {
#pragma unroll
        for (int c = 0; c < 4; ++c) {
            int nn_ = n0 + c * 16 + l16;
#pragma unroll
            for (int i = 0; i < 4; ++i) {
                int m = mrow_base + r * 16 + lhalf * 4 + i;
                if (m >= M) continue;
                if constexpr (EPI == 0) {
                    int pc = swz_elem(nn_, m);
#pragma unroll
                    for (int g = 0; g < NG; ++g) {
                        float v = acc[g][r][c][i];
                        if (bias != nullptr && nn_ < HIDDEN) v += bias[g * HIDDEN + nn_];
                        C1[(size_t)m * ldc + g * 320 + pc] = f2bf(v);
                    }
                } else { // EPI == 2
                    if (nn_ < HIDDEN) {
                        float v = acc[0][r][c][i] + (bias ? bias[nn_] : 0.f);
                        v = fmaxf(v, 0.f);
                        if (omask) v *= omask[m];
                        outp[(size_t)m * HIDDEN + nn_] = v;
                    }
                }
            }
        }
    }
}

// ---------------------------------------------------------------------------
// Fused GRU GEMM, two STATIC phases (all gate indices compile-time):
//   phase A (ks 0..4):  A = fb_p,  gates {0,1,2}  (r, z, i_n)
//   phase B (ks 5..14): A = hbuf,  gates {0,1,3}  (r, z, h_n)
// Zero-block skip is bit-exact. Epilogue applies the GRU nonlinearity.
// ---------------------------------------------------------------------------
__global__ __launch_bounds__(256, 2) void gemm_gru_k(
    const u16* __restrict__ A1,   // fb_p [NB_PAD][160] swizzled
    const u16* __restrict__ A2,   // hbuf [NB_PAD][320] swizzled
    const u16* __restrict__ Bw,   // W4 [4][320][480] swizzled
    const float* __restrict__ bias,  // [4*320]
    const u16* __restrict__ hbuf,
    u16* __restrict__ msg_out)
{
    __shared__ __align__(16) u16 lsA[128 * 32];
    __shared__ __align__(16) u16 lsB[4 * 64 * 32];

    const int tid = threadIdx.x;
    const int wv = tid >> 6, ln = tid & 63;
    const int m0 = blockIdx.x * 128;
    const int n0 = blockIdx.y * 64;
    const int lhalf = ln >> 4, l16 = ln & 15;
    const int aoff = ((lhalf ^ ((l16 >> 1) & 3))) * 8;

    f32x4 acc0[2][4], acc1[2][4], acc2[2][4], acc3[2][4];
#pragma unroll
    for (int r = 0; r < 2; ++r)
#pragma unroll
        for (int c = 0; c < 4; ++c) {
            f32x4 z = {0.f, 0.f, 0.f, 0.f};
            acc0[r][c] = z; acc1[r][c] = z; acc2[r][c] = z; acc3[r][c] = z;
        }

    // ---- phase A: ks 0..4, A = fb (ld 320B), gates 0,1,2 ----
    for (int ks = 0; ks < 5; ++ks) {
        __syncthreads();
        const char* Abase = (const char*)A1 + (size_t)ks * 64;
#pragma unroll
        for (int c = 0; c < 2; ++c) {
            int chunk = wv * 2 + c;
            int idx = chunk * 64 + ln;
            int row = idx >> 2, kb = (idx & 3) * 16;
            async_copy16(Abase + (size_t)(m0 + row) * (KB_PAD * 2) + kb, &lsA[chunk * 512]);
        }
        {
            int idx = wv * 64 + ln;
            int n = idx >> 2, kb = (idx & 3) * 16;
            size_t col = (size_t)ks * 64 + kb;
#pragma unroll
            for (int g = 0; g < 3; ++g)
                async_copy16((const char*)Bw + (size_t)(g * 320 + n0 + n) * 960 + col,
                             &lsB[g * 2048 + wv * 512]);
        }
        __syncthreads();

        bf16x8 af[2];
#pragma unroll
        for (int r = 0; r < 2; ++r)
            af[r] = *(const bf16x8*)&lsA[(wv * 32 + r * 16 + l16) * 32 + aoff];
#pragma unroll
        for (int c = 0; c < 4; ++c) {
            bf16x8 b0 = *(const bf16x8*)&lsB[0 * 2048 + (c * 16 + l16) * 32 + aoff];
            bf16x8 b1 = *(const bf16x8*)&lsB[1 * 2048 + (c * 16 + l16) * 32 + aoff];
            bf16x8 b2 = *(const bf16x8*)&lsB[2 * 2048 + (c * 16 + l16) * 32 + aoff];
#pragma unroll
            for (int r = 0; r < 2; ++r) {
                acc0[r][c] = __builtin_amdgcn_mfma_f32_16x16x32_bf16(af[r], b0, acc0[r][c], 0, 0, 0);
                acc1[r][c] = __builtin_amdgcn_mfma_f32_16x16x32_bf16(af[r], b1, acc1[r][c], 0, 0, 0);
                acc2[r][c] = __builtin_amdgcn_mfma_f32_16x16x32_bf16(af[r], b2, acc2[r][c], 0, 0, 0);
            }
        }
    }

    // ---- phase B: ks 5..14, A = h (ld 640B), gates 0,1,3 ----
    for (int ks = 5; ks < 15; ++ks) {
        __syncthreads();
        const char* Abase = (const char*)A2 + (size_t)(ks - 5) * 64;
#pragma unroll
        for (int c = 0; c < 2; ++c) {
            int chunk = wv * 2 + c;
            int idx = chunk * 64 + ln;
            int row = idx >> 2, kb = (idx & 3) * 16;
            async_copy16(Abase + (size_t)(m0 + row) * (HP * 2) + kb, &lsA[chunk * 512]);
        }
        {
            int idx = wv * 64 + ln;
            int n = idx >> 2, kb = (idx & 3) * 16;
            size_t col = (size_t)ks * 64 + kb;
            async_copy16((const char*)Bw + (size_t)(0 * 320 + n0 + n) * 960 + col,
                         &lsB[0 * 2048 + wv * 512]);
            async_copy16((const char*)Bw + (size_t)(1 * 320 + n0 + n) * 960 + col,
                         &lsB[1 * 2048 + wv * 512]);
            async_copy16((const char*)Bw + (size_t)(3 * 320 + n0 + n) * 960 + col,
                         &lsB[3 * 2048 + wv * 512]);
        }
        __syncthreads();

        bf16x8 af[2];
#pragma unroll
        for (int r = 0; r < 2; ++r)
            af[r] = *(const bf16x8*)&lsA[(wv * 32 + r * 16 + l16) * 32 + aoff];
#pragma unroll
        for (int c = 0; c < 4; ++c) {
            bf16x8 b0 = *(const bf16x8*)&lsB[0 * 2048 + (c * 16 + l16) * 32 + aoff];
            bf16x8 b1 = *(const bf16x8*)&lsB[1 * 2048 + (c * 16 + l16) * 32 + aoff];
            bf16x8 b3 = *(const bf16x8*)&lsB[3 * 2048 + (c * 16 + l16) * 32 + aoff];
#pragma unroll
            for (int r = 0; r < 2; ++r) {
                acc0[r][c] = __builtin_amdgcn_mfma_f32_16x16x32_bf16(af[r], b0, acc0[r][c], 0, 0, 0);
                acc1[r][c] = __builtin_amdgcn_mfma_f32_16x16x32_bf16(af[r], b1, acc1[r][c], 0, 0, 0);
                acc3[r][c] = __builtin_amdgcn_mfma_f32_16x16x32_bf16(af[r], b3, acc3[r][c], 0, 0, 0);
            }
        }
    }

    const int mrow_base = m0 + wv * 32;
#pragma unroll
    for (int r = 0; r < 2; ++r) {
#pragma unroll
        for (int c = 0; c < 4; ++c) {
            int nn_ = n0 + c * 16 + l16;
#pragma unroll
            for (int i = 0; i < 4; ++i) {
                int m = mrow_base + r * 16 + lhalf * 4 + i;
                if (m >= N_BONDS) continue;
                int pc = swz_elem(nn_, m);
                float rl  = acc0[r][c][i] + bias[nn_];
                float zl  = acc1[r][c][i] + bias[320 + nn_];
                float in_ = acc2[r][c][i] + bias[640 + nn_];
                float hn_ = acc3[r][c][i] + bias[960 + nn_];
                float hv = bf2f(hbuf[(size_t)m * HP + pc]);
                float rr = sigm(rl);
                float zz = sigm(zl);
                float nv = tanh_s(in_ + rr * hn_);
                float msg = (1.f - zz) * nv + zz * hv;
                if (m == 0) msg = 0.f;
                msg_out[(size_t)m * HP + pc] = f2bf(msg);
            }
        }
    }
}

// a_message[a,:] = sum_j message[a2b[a,j],:]  (bf16, swizzled rows both sides)
__global__ __launch_bounds__(256) void gather_sum_k(
    const u16* __restrict__ msg, const int* __restrict__ a2b, u16* __restrict__ amsg)
{
    int u = blockIdx.x * 256 + threadIdx.x;
    if (u >= N_ATOMS * 40) return;
    int a = u / 40, c = u - a * 40;
    const uint4* mp = (const uint4*)msg;
    float s[8];
#pragma unroll
    for (int t = 0; t < 8; ++t) s[t] = 0.f;
#pragma unroll
    for (int j = 0; j < MAX_NB; ++j) {
        int b = a2b[a * MAX_NB + j];
        uint4 v = mp[(size_t)b * 40 + swz_chunk(c, b)];
        s[0] += bf2f((u16)(v.x & 0xffff)); s[1] += bf2f((u16)(v.x >> 16));
        s[2] += bf2f((u16)(v.y & 0xffff)); s[3] += bf2f((u16)(v.y >> 16));
        s[4] += bf2f((u16)(v.z & 0xffff)); s[5] += bf2f((u16)(v.z >> 16));
        s[6] += bf2f((u16)(v.w & 0xffff)); s[7] += bf2f((u16)(v.w >> 16));
    }
    uint4 o;
    o.x = (uint32)f2bf(s[0]) | ((uint32)f2bf(s[1]) << 16);
    o.y = (uint32)f2bf(s[2]) | ((uint32)f2bf(s[3]) << 16);
    o.z = (uint32)f2bf(s[4]) | ((uint32)f2bf(s[5]) << 16);
    o.w = (uint32)f2bf(s[6]) | ((uint32)f2bf(s[7]) << 16);
    ((uint4*)amsg)[(size_t)a * 40 + swz_chunk(c, a)] = o;
}

// h[b,:] = amsg[b2a[b],:] - msg[b2revb[b],:]  (swizzled rows everywhere)
__global__ __launch_bounds__(256) void build_h_k(
    const u16* __restrict__ amsg, const u16* __restrict__ msg,
    const int* __restrict__ b2a, const int* __restrict__ b2revb, u16* __restrict__ h)
{
    int u = blockIdx.x * 256 + threadIdx.x;
    if (u >= N_BONDS * 40) return;
    int b = u / 40, c = u - b * 40;
    int ra = b2a[b], rm = b2revb[b];
    uint4 va = ((const uint4*)amsg)[(size_t)ra * 40 + swz_chunk(c, ra)];
    uint4 vm = ((const uint4*)msg)[(size_t)rm * 40 + swz_chunk(c, rm)];
    uint4 o;
    o.x = (uint32)f2bf(bf2f((u16)(va.x & 0xffff)) - bf2f((u16)(vm.x & 0xffff)))
        | ((uint32)f2bf(bf2f((u16)(va.x >> 16)) - bf2f((u16)(vm.x >> 16))) << 16);
    o.y = (uint32)f2bf(bf2f((u16)(va.y & 0xffff)) - bf2f((u16)(vm.y & 0xffff)))
        | ((uint32)f2bf(bf2f((u16)(va.y >> 16)) - bf2f((u16)(vm.y >> 16))) << 16);
    o.z = (uint32)f2bf(bf2f((u16)(va.z & 0xffff)) - bf2f((u16)(vm.z & 0xffff)))
        | ((uint32)f2bf(bf2f((u16)(va.z >> 16)) - bf2f((u16)(vm.z >> 16))) << 16);
    o.w = (uint32)f2bf(bf2f((u16)(va.w & 0xffff)) - bf2f((u16)(vm.w & 0xffff)))
        | ((uint32)f2bf(bf2f((u16)(va.w >> 16)) - bf2f((u16)(vm.w >> 16))) << 16);
    ((uint4*)h)[(size_t)b * 40 + swz_chunk(c, b)] = o;
}

// pad+cast fp32 -> bf16, swizzled destination
__global__ __launch_bounds__(256) void padcast_k(
    const float* __restrict__ src, int srows, int scols,
    u16* __restrict__ dst, int drows, int dcols)
{
    int idx = blockIdx.x * 256 + threadIdx.x;
    if (idx >= drows * dcols) return;
    int r = idx / dcols, c = idx - r * dcols;
    float v = (r < srows && c < scols) ? src[(size_t)r * scols + c] : 0.f;
    dst[(size_t)r * dcols + swz_elem(c, r)] = f2bf(v);
}

// Wf[900][160] fp32 = W_ih[900][300] @ W_i[300][147] (cols >=147 zero), unswizzled
__global__ __launch_bounds__(256) void wf_k(
    const float* __restrict__ W_ih, const float* __restrict__ W_i, float* __restrict__ Wf)
{
    int idx = blockIdx.x * 256 + threadIdx.x;
    if (idx >= 900 * 160) return;
    int r = idx / 160, c = idx - r * 160;
    float s = 0.f;
    if (c < BOND_FDIM) {
        for (int k = 0; k < HIDDEN; ++k)
            s += W_ih[(size_t)r * HIDDEN + k] * W_i[(size_t)k * BOND_FDIM + c];
    }
    Wf[idx] = s;
}

// W4[4][320][480] bf16 swizzled: r/z: [Wf_g | W_hh_g]; i_n: [Wf_n | 0]; h_n: [0 | W_hh_n]
__global__ __launch_bounds__(256) void prep_W4_k(
    const float* __restrict__ Wf, const float* __restrict__ W_hh, u16* __restrict__ W4)
{
    int idx = blockIdx.x * 256 + threadIdx.x;
    if (idx >= 4 * HP * 480) return;
    int g = idx / (HP * 480); int rem = idx - g * HP * 480;
    int n = rem / 480, k = rem - n * 480;
    float v = 0.f;
    if (n < HIDDEN) {
        if (g <= 1) {
            if (k < KB_PAD) v = Wf[(size_t)(g * HIDDEN + n) * 160 + k];
            else if (k < KB_PAD + HIDDEN) v = W_hh[(size_t)(g * HIDDEN + n) * HIDDEN + (k - KB_PAD)];
        } else if (g == 2) {
            if (k < KB_PAD) v = Wf[(size_t)(2 * HIDDEN + n) * 160 + k];
        } else {
            if (k >= KB_PAD && k < KB_PAD + HIDDEN) v = W_hh[(size_t)(2 * HIDDEN + n) * HIDDEN + (k - KB_PAD)];
        }
    }
    W4[(size_t)(g * HP + n) * 480 + swz_elem(k, n)] = f2bf(v);
}

// bias4[4*320]: r: b_ih_r+b_hh_r; z: b_ih_z+b_hh_z; i_n: b_ih_n; h_n: b_hh_n
__global__ __launch_bounds__(256) void bias4_k(
    const float* __restrict__ b_ih, const float* __restrict__ b_hh, float* __restrict__ b4)
{
    int idx = blockIdx.x * 256 + threadIdx.x;
    if (idx >= 4 * HP) return;
    int g = idx / HP, n = idx - g * HP;
    float v = 0.f;
    if (n < HIDDEN) {
        if (g == 0) v = b_ih[n] + b_hh[n];
        else if (g == 1) v = b_ih[HIDDEN + n] + b_hh[HIDDEN + n];
        else if (g == 2) v = b_ih[2 * HIDDEN + n];
        else v = b_hh[2 * HIDDEN + n];
    }
    b4[idx] = v;
}

// W_o [300][433] -> [320][480] swizzled: k<133 atom part, k in [160,460) hidden part
__global__ __launch_bounds__(256) void padWo_k(const float* __restrict__ src, u16* __restrict__ dst)
{
    int idx = blockIdx.x * 256 + threadIdx.x;
    if (idx >= HP * 480) return;
    int n = idx / 480, k = idx - n * 480;
    float v = 0.f;
    if (n < HIDDEN) {
        if (k < ATOM_FDIM) v = src[(size_t)n * 433 + k];
        else if (k >= KA_PAD && k < KA_PAD + HIDDEN) v = src[(size_t)n * 433 + ATOM_FDIM + (k - KA_PAD)];
    }
    dst[(size_t)n * 480 + swz_elem(k, n)] = f2bf(v);
}

__global__ __launch_bounds__(256) void sentinel_k(float* __restrict__ out, int n)
{
    int i = blockIdx.x * 256 + threadIdx.x;
    if (i < n) out[i] = 31415.0f;
}

extern "C" void kernel_launch(void* const* d_in, const int* in_sizes, int n_in,
                              void* d_out, int out_size, void* d_ws, size_t ws_size,
                              hipStream_t stream)
{
    const float* f_atoms = (const float*)d_in[0];
    const float* f_bonds = (const float*)d_in[1];
    const int*   a2b     = (const int*)d_in[2];
    const int*   b2a     = (const int*)d_in[3];
    const int*   b2revb  = (const int*)d_in[4];
    const float* maskp   = (const float*)d_in[8];
    const float* W_i     = (const float*)d_in[9];
    const float* W_ih    = (const float*)d_in[10];
    const float* W_hh    = (const float*)d_in[11];
    const float* b_ih    = (const float*)d_in[12];
    const float* b_hh    = (const float*)d_in[13];
    const float* W_o_w   = (const float*)d_in[14];
    const float* W_o_b   = (const float*)d_in[15];
    float* out = (float*)d_out;

    char* ws = (char*)d_ws;
    size_t off = 0;
    auto alloc = [&](size_t bytes) -> char* {
        char* p = ws + off;
        off += (bytes + 255) & ~(size_t)255;
        return p;
    };
    u16*   Wi_p   = (u16*)alloc((size_t)HP * KB_PAD * 2);
    u16*   W4     = (u16*)alloc((size_t)4 * HP * 480 * 2);
    u16*   Wo_p   = (u16*)alloc((size_t)HP * 480 * 2);
    float* bias4  = (float*)alloc((size_t)4 * HP * 4);
    float* Wf     = (float*)alloc((size_t)900 * 160 * 4);
    u16*   fa_p   = (u16*)alloc((size_t)NA_PAD * KA_PAD * 2);
    u16*   fb_p   = (u16*)alloc((size_t)NB_PAD * KB_PAD * 2);
    u16*   message= (u16*)alloc((size_t)NB_PAD * HP * 2);
    u16*   hbuf   = (u16*)alloc((size_t)NB_PAD * HP * 2);
    u16*   amsg   = (u16*)alloc((size_t)NA_PAD * HP * 2);

    if (off > ws_size) {
        sentinel_k<<<(out_size + 255) / 256, 256, 0, stream>>>(out, out_size);
        return;
    }

    // --- prep (all bf16 buffers written pre-swizzled) ---
    padcast_k<<<(HP * KB_PAD + 255) / 256, 256, 0, stream>>>(W_i, HIDDEN, BOND_FDIM, Wi_p, HP, KB_PAD);
    padcast_k<<<(NB_PAD * KB_PAD + 255) / 256, 256, 0, stream>>>(f_bonds, N_BONDS, BOND_FDIM, fb_p, NB_PAD, KB_PAD);
    padcast_k<<<(NA_PAD * KA_PAD + 255) / 256, 256, 0, stream>>>(f_atoms, N_ATOMS, ATOM_FDIM, fa_p, NA_PAD, KA_PAD);
    wf_k<<<(900 * 160 + 255) / 256, 256, 0, stream>>>(W_ih, W_i, Wf);
    prep_W4_k<<<(4 * HP * 480 + 255) / 256, 256, 0, stream>>>(Wf, W_hh, W4);
    bias4_k<<<(4 * HP + 255) / 256, 256, 0, stream>>>(b_ih, b_hh, bias4);
    padWo_k<<<(HP * 480 + 255) / 256, 256, 0, stream>>>(W_o_w, Wo_p);

    dim3 blk(256);
    dim3 gB(NB_PAD / 128, 5);
    // message = inp = f_bonds @ W_i.T
    gemm_k<1, 0><<<gB, blk, 0, stream>>>(fb_p, KB_PAD * 2, nullptr, 0, 1 << 30, Wi_p, KB_PAD * 2,
                                         5, N_BONDS, message, HP,
                                         nullptr, nullptr, nullptr);
    for (int d = 0; d < DEPTH - 1; ++d) {
        gather_sum_k<<<(N_ATOMS * 40 + 255) / 256, 256, 0, stream>>>(message, a2b, amsg);
        build_h_k<<<(N_BONDS * 40 + 255) / 256, 256, 0, stream>>>(amsg, message, b2a, b2revb, hbuf);
        gemm_gru_k<<<gB, blk, 0, stream>>>(fb_p, hbuf, W4, bias4, hbuf, message);
    }
    gather_sum_k<<<(N_ATOMS * 40 + 255) / 256, 256, 0, stream>>>(message, a2b, amsg);
    dim3 gO(NA_PAD / 128, 5);
    gemm_k<1, 2><<<gO, blk, 0, stream>>>(fa_p, KA_PAD * 2, amsg, HP * 2, 5, Wo_p, 480 * 2,
                                         15, N_ATOMS, nullptr, 0,
                                         W_o_b, out, maskp);
}

// Round 5
// 1488.727 us; speedup vs baseline: 1.0234x; 1.0116x over previous
//
#include <hip/hip_runtime.h>
#include <hip/hip_bf16.h>
#include <stdint.h>

#define N_ATOMS 40000
#define N_BONDS 90000
#define MAX_NB 6
#define ATOM_FDIM 133
#define BOND_FDIM 147
#define HIDDEN 300
#define DEPTH 6

// padded dims
#define KB_PAD 160      // bond fdim 147 -> 160 (5 ksteps of 32)
#define KA_PAD 160      // atom fdim 133 -> 160
#define HP 320          // hidden 300 -> 320 (10 ksteps of 32)
#define NB_PAD 90112    // bonds padded to mult of 128
#define NA_PAD 40064    // atoms padded to mult of 128

typedef unsigned short u16;
typedef unsigned int uint32;

typedef __bf16 bf16x8 __attribute__((ext_vector_type(8)));
typedef float f32x4 __attribute__((ext_vector_type(4)));

#define GLOBAL_AS __attribute__((address_space(1)))
#define LDS_AS __attribute__((address_space(3)))

__device__ __forceinline__ void async_copy16(const void* g, void* l) {
    __builtin_amdgcn_global_load_lds((GLOBAL_AS void*)(void*)g,
                                     (LDS_AS void*)l, 16, 0, 0);
}

// raw barrier WITHOUT the compiler's implicit s_waitcnt vmcnt(0) drain
__device__ __forceinline__ void raw_barrier() {
    asm volatile("s_barrier" ::: "memory");
}
// s_waitcnt vmcnt(N) only (exp=7, lgkm=15 -> no wait): imm = 0xF70 | N
#define WAITCNT_VM(N) __builtin_amdgcn_s_waitcnt(0xF70 | (N))

__device__ __forceinline__ float bf2f(u16 s) {
    union { uint32 u; float f; } v; v.u = ((uint32)s) << 16; return v.f;
}
__device__ __forceinline__ u16 f2bf(float f) {
    union { float f; uint32 u; } v; v.f = f;
    uint32 r = v.u + 0x7fffu + ((v.u >> 16) & 1u);
    return (u16)(r >> 16);
}
__device__ __forceinline__ float sigm(float x) { return 1.f / (1.f + __expf(-x)); }
__device__ __forceinline__ float tanh_s(float x) {
    float e = __expf(-2.f * fabsf(x));
    float t = (1.f - e) / (1.f + e);
    return x >= 0.f ? t : -t;
}

// --- XOR chunk swizzle (R3: verified SQ_LDS_BANK_CONFLICT == 0) ---
__device__ __forceinline__ int swz_chunk(int c, int row) {
    return (c & ~3) | ((c & 3) ^ ((row >> 1) & 3));
}
__device__ __forceinline__ int swz_elem(int e, int row) {
    return (e & ~31) | (((((e >> 3) & 3)) ^ ((row >> 1) & 3)) << 3) | (e & 7);
}

// ---------------------------------------------------------------------------
// Generic GEMM with double-buffered LDS pipeline.
// C_g[M x 320] = A[M x K] @ B_g[320 x K]^T, bf16, fp32 acc.
// Tile 128 x 64, 4 waves. EPI 0: bf16 store (+bias). EPI 2: bias+relu+mask.
// Pipeline: prefetch kstep k+1 while computing k; raw s_barrier + vmcnt(2+NG).
// ---------------------------------------------------------------------------
template<int NG, int EPI>
__global__ __launch_bounds__(256, 2) void gemm_k(
    const u16* __restrict__ A, int ldaB,
    const u16* __restrict__ A2, int lda2B, int ksplit,
    const u16* __restrict__ Bw, int ldbB,
    int ksteps, int M,
    u16* __restrict__ C1, int ldc,
    const float* __restrict__ bias,
    float* __restrict__ outp, const float* __restrict__ omask)
{
    __shared__ __align__(16) u16 lsA[2 * 128 * 32];
    __shared__ __align__(16) u16 lsB[2 * NG * 64 * 32];

    const int tid = threadIdx.x;
    const int wv = tid >> 6, ln = tid & 63;
    const int m0 = blockIdx.x * 128;
    const int n0 = blockIdx.y * 64;
    const int lhalf = ln >> 4, l16 = ln & 15;
    const int aoff = ((lhalf ^ ((l16 >> 1) & 3))) * 8;

    f32x4 acc[NG][2][4];
#pragma unroll
    for (int g = 0; g < NG; ++g)
#pragma unroll
        for (int r = 0; r < 2; ++r)
#pragma unroll
            for (int c = 0; c < 4; ++c) { f32x4 z = {0.f, 0.f, 0.f, 0.f}; acc[g][r][c] = z; }

    auto stage = [&](int ks, int buf) {
        const char* Abase; int ldA;
        if (ks < ksplit) { Abase = (const char*)A + (size_t)ks * 64; ldA = ldaB; }
        else             { Abase = (const char*)A2 + (size_t)(ks - ksplit) * 64; ldA = lda2B; }
#pragma unroll
        for (int c = 0; c < 2; ++c) {
            int chunk = wv * 2 + c;
            int idx = chunk * 64 + ln;
            int row = idx >> 2, kb = (idx & 3) * 16;
            async_copy16(Abase + (size_t)(m0 + row) * ldA + kb, &lsA[buf * 4096 + chunk * 512]);
        }
        int idx = wv * 64 + ln;
        int n = idx >> 2, kb = (idx & 3) * 16;
#pragma unroll
        for (int g = 0; g < NG; ++g)
            async_copy16((const char*)Bw + (size_t)(g * 320 + n0 + n) * ldbB + (size_t)ks * 64 + kb,
                         &lsB[buf * (NG * 2048) + g * 2048 + wv * 512]);
    };

    stage(0, 0);
    for (int ks = 0; ks < ksteps; ++ks) {
        int buf = ks & 1;
        if (ks + 1 < ksteps) {
            stage(ks + 1, buf ^ 1);
            WAITCNT_VM(2 + NG);   // current kstep's loads done; prefetch stays in flight
        } else {
            WAITCNT_VM(0);
        }
        raw_barrier();

        bf16x8 af[2];
#pragma unroll
        for (int r = 0; r < 2; ++r)
            af[r] = *(const bf16x8*)&lsA[buf * 4096 + (wv * 32 + r * 16 + l16) * 32 + aoff];
#pragma unroll
        for (int g = 0; g < NG; ++g) {
#pragma unroll
            for (int c = 0; c < 4; ++c) {
                bf16x8 bfv = *(const bf16x8*)&lsB[buf * (NG * 2048) + g * 2048 + (c * 16 + l16) * 32 + aoff];
#pragma unroll
                for (int r = 0; r < 2; ++r)
                    acc[g][r][c] = __builtin_amdgcn_mfma_f32_16x16x32_bf16(af[r], bfv, acc[g][r][c], 0, 0, 0);
            }
        }
        raw_barrier();   // all waves done reading buf -> next iter may overwrite it
    }

    const int mrow_base = m0 + wv * 32;
#pragma unroll
    for (int r = 0; r < 2; ++r) {
#pragma unroll
        for (int c = 0; c < 4; ++c) {
            int nn_ = n0 + c * 16 + l16;
#pragma unroll
            for (int i = 0; i < 4; ++i) {
                int m = mrow_base + r * 16 + lhalf * 4 + i;
                if (m >= M) continue;
                if constexpr (EPI == 0) {
                    int pc = swz_elem(nn_, m);
#pragma unroll
                    for (int g = 0; g < NG; ++g) {
                        float v = acc[g][r][c][i];
                        if (bias != nullptr && nn_ < HIDDEN) v += bias[g * HIDDEN + nn_];
                        C1[(size_t)m * ldc + g * 320 + pc] = f2bf(v);
                    }
                } else { // EPI == 2
                    if (nn_ < HIDDEN) {
                        float v = acc[0][r][c][i] + (bias ? bias[nn_] : 0.f);
                        v = fmaxf(v, 0.f);
                        if (omask) v *= omask[m];
                        outp[(size_t)m * HIDDEN + nn_] = v;
                    }
                }
            }
        }
    }
}

// ---------------------------------------------------------------------------
// Fused GRU GEMM, double-buffered pipeline, two static phases:
//   phase A (ks 0..4):  A = fb_p,  B slots {0,1,2} = gates {r, z, i_n}
//   phase B (ks 5..14): A = hbuf,  B slots {0,1,2} = gates {r, z, h_n}
// (gate h_n lives in LDS slot 2 during phase B; acc target is static per phase)
// ---------------------------------------------------------------------------
__global__ __launch_bounds__(256, 2) void gemm_gru_k(
    const u16* __restrict__ A1,   // fb_p [NB_PAD][160] swizzled
    const u16* __restrict__ A2,   // hbuf [NB_PAD][320] swizzled
    const u16* __restrict__ Bw,   // W4 [4][320][480] swizzled
    const float* __restrict__ bias,  // [4*320]
    const u16* __restrict__ hbuf,
    u16* __restrict__ msg_out)
{
    __shared__ __align__(16) u16 lsA[2 * 128 * 32];     // 16 KB
    __shared__ __align__(16) u16 lsB[2 * 3 * 64 * 32];  // 24 KB

    const int tid = threadIdx.x;
    const int wv = tid >> 6, ln = tid & 63;
    const int m0 = blockIdx.x * 128;
    const int n0 = blockIdx.y * 64;
    const int lhalf = ln >> 4, l16 = ln & 15;
    const int aoff = ((lhalf ^ ((l16 >> 1) & 3))) * 8;

    f32x4 acc0[2][4], acc1[2][4], acc2[2][4], acc3[2][4];
#pragma unroll
    for (int r = 0; r < 2; ++r)
#pragma unroll
        for (int c = 0; c < 4; ++c) {
            f32x4 z = {0.f, 0.f, 0.f, 0.f};
            acc0[r][c] = z; acc1[r][c] = z; acc2[r][c] = z; acc3[r][c] = z;
        }

    auto stage = [&](int ks, int buf) {
        const bool phA = (ks < 5);
        const char* Abase = phA ? ((const char*)A1 + (size_t)ks * 64)
                                : ((const char*)A2 + (size_t)(ks - 5) * 64);
        const int ldA = phA ? (KB_PAD * 2) : (HP * 2);
#pragma unroll
        for (int c = 0; c < 2; ++c) {
            int chunk = wv * 2 + c;
            int idx = chunk * 64 + ln;
            int row = idx >> 2, kb = (idx & 3) * 16;
            async_copy16(Abase + (size_t)(m0 + row) * ldA + kb, &lsA[buf * 4096 + chunk * 512]);
        }
        int idx = wv * 64 + ln;
        int n = idx >> 2, kb = (idx & 3) * 16;
        size_t col = (size_t)ks * 64 + kb;
        const int g2 = phA ? 2 : 3;
        async_copy16((const char*)Bw + (size_t)(0 * 320 + n0 + n) * 960 + col,
                     &lsB[buf * 6144 + 0 * 2048 + wv * 512]);
        async_copy16((const char*)Bw + (size_t)(1 * 320 + n0 + n) * 960 + col,
                     &lsB[buf * 6144 + 1 * 2048 + wv * 512]);
        async_copy16((const char*)Bw + (size_t)(g2 * 320 + n0 + n) * 960 + col,
                     &lsB[buf * 6144 + 2 * 2048 + wv * 512]);
    };

    stage(0, 0);
    for (int ks = 0; ks < 15; ++ks) {
        int buf = ks & 1;
        if (ks < 14) {
            stage(ks + 1, buf ^ 1);
            WAITCNT_VM(5);        // wait current kstep's 5 loads; keep prefetch in flight
        } else {
            WAITCNT_VM(0);
        }
        raw_barrier();

        bf16x8 af[2];
#pragma unroll
        for (int r = 0; r < 2; ++r)
            af[r] = *(const bf16x8*)&lsA[buf * 4096 + (wv * 32 + r * 16 + l16) * 32 + aoff];
        if (ks < 5) {
#pragma unroll
            for (int c = 0; c < 4; ++c) {
                bf16x8 b0 = *(const bf16x8*)&lsB[buf * 6144 + 0 * 2048 + (c * 16 + l16) * 32 + aoff];
                bf16x8 b1 = *(const bf16x8*)&lsB[buf * 6144 + 1 * 2048 + (c * 16 + l16) * 32 + aoff];
                bf16x8 b2 = *(const bf16x8*)&lsB[buf * 6144 + 2 * 2048 + (c * 16 + l16) * 32 + aoff];
#pragma unroll
                for (int r = 0; r < 2; ++r) {
                    acc0[r][c] = __builtin_amdgcn_mfma_f32_16x16x32_bf16(af[r], b0, acc0[r][c], 0, 0, 0);
                    acc1[r][c] = __builtin_amdgcn_mfma_f32_16x16x32_bf16(af[r], b1, acc1[r][c], 0, 0, 0);
                    acc2[r][c] = __builtin_amdgcn_mfma_f32_16x16x32_bf16(af[r], b2, acc2[r][c], 0, 0, 0);
                }
            }
        } else {
#pragma unroll
            for (int c = 0; c < 4; ++c) {
                bf16x8 b0 = *(const bf16x8*)&lsB[buf * 6144 + 0 * 2048 + (c * 16 + l16) * 32 + aoff];
                bf16x8 b1 = *(const bf16x8*)&lsB[buf * 6144 + 1 * 2048 + (c * 16 + l16) * 32 + aoff];
                bf16x8 b3 = *(const bf16x8*)&lsB[buf * 6144 + 2 * 2048 + (c * 16 + l16) * 32 + aoff];
#pragma unroll
                for (int r = 0; r < 2; ++r) {
                    acc0[r][c] = __builtin_amdgcn_mfma_f32_16x16x32_bf16(af[r], b0, acc0[r][c], 0, 0, 0);
                    acc1[r][c] = __builtin_amdgcn_mfma_f32_16x16x32_bf16(af[r], b1, acc1[r][c], 0, 0, 0);
                    acc3[r][c] = __builtin_amdgcn_mfma_f32_16x16x32_bf16(af[r], b3, acc3[r][c], 0, 0, 0);
                }
            }
        }
        raw_barrier();
    }

    const int mrow_base = m0 + wv * 32;
#pragma unroll
    for (int r = 0; r < 2; ++r) {
#pragma unroll
        for (int c = 0; c < 4; ++c) {
            int nn_ = n0 + c * 16 + l16;
#pragma unroll
            for (int i = 0; i < 4; ++i) {
                int m = mrow_base + r * 16 + lhalf * 4 + i;
                if (m >= N_BONDS) continue;
                int pc = swz_elem(nn_, m);
                float rl  = acc0[r][c][i] + bias[nn_];
                float zl  = acc1[r][c][i] + bias[320 + nn_];
                float in_ = acc2[r][c][i] + bias[640 + nn_];
                float hn_ = acc3[r][c][i] + bias[960 + nn_];
                float hv = bf2f(hbuf[(size_t)m * HP + pc]);
                float rr = sigm(rl);
                float zz = sigm(zl);
                float nv = tanh_s(in_ + rr * hn_);
                float msg = (1.f - zz) * nv + zz * hv;
                if (m == 0) msg = 0.f;
                msg_out[(size_t)m * HP + pc] = f2bf(msg);
            }
        }
    }
}

// a_message[a,:] = sum_j message[a2b[a,j],:]  (bf16, swizzled rows both sides)
__global__ __launch_bounds__(256) void gather_sum_k(
    const u16* __restrict__ msg, const int* __restrict__ a2b, u16* __restrict__ amsg)
{
    int u = blockIdx.x * 256 + threadIdx.x;
    if (u >= N_ATOMS * 40) return;
    int a = u / 40, c = u - a * 40;
    const uint4* mp = (const uint4*)msg;
    float s[8];
#pragma unroll
    for (int t = 0; t < 8; ++t) s[t] = 0.f;
#pragma unroll
    for (int j = 0; j < MAX_NB; ++j) {
        int b = a2b[a * MAX_NB + j];
        uint4 v = mp[(size_t)b * 40 + swz_chunk(c, b)];
        s[0] += bf2f((u16)(v.x & 0xffff)); s[1] += bf2f((u16)(v.x >> 16));
        s[2] += bf2f((u16)(v.y & 0xffff)); s[3] += bf2f((u16)(v.y >> 16));
        s[4] += bf2f((u16)(v.z & 0xffff)); s[5] += bf2f((u16)(v.z >> 16));
        s[6] += bf2f((u16)(v.w & 0xffff)); s[7] += bf2f((u16)(v.w >> 16));
    }
    uint4 o;
    o.x = (uint32)f2bf(s[0]) | ((uint32)f2bf(s[1]) << 16);
    o.y = (uint32)f2bf(s[2]) | ((uint32)f2bf(s[3]) << 16);
    o.z = (uint32)f2bf(s[4]) | ((uint32)f2bf(s[5]) << 16);
    o.w = (uint32)f2bf(s[6]) | ((uint32)f2bf(s[7]) << 16);
    ((uint4*)amsg)[(size_t)a * 40 + swz_chunk(c, a)] = o;
}

// h[b,:] = amsg[b2a[b],:] - msg[b2revb[b],:]  (swizzled rows everywhere)
__global__ __launch_bounds__(256) void build_h_k(
    const u16* __restrict__ amsg, const u16* __restrict__ msg,
    const int* __restrict__ b2a, const int* __restrict__ b2revb, u16* __restrict__ h)
{
    int u = blockIdx.x * 256 + threadIdx.x;
    if (u >= N_BONDS * 40) return;
    int b = u / 40, c = u - b * 40;
    int ra = b2a[b], rm = b2revb[b];
    uint4 va = ((const uint4*)amsg)[(size_t)ra * 40 + swz_chunk(c, ra)];
    uint4 vm = ((const uint4*)msg)[(size_t)rm * 40 + swz_chunk(c, rm)];
    uint4 o;
    o.x = (uint32)f2bf(bf2f((u16)(va.x & 0xffff)) - bf2f((u16)(vm.x & 0xffff)))
        | ((uint32)f2bf(bf2f((u16)(va.x >> 16)) - bf2f((u16)(vm.x >> 16))) << 16);
    o.y = (uint32)f2bf(bf2f((u16)(va.y & 0xffff)) - bf2f((u16)(vm.y & 0xffff)))
        | ((uint32)f2bf(bf2f((u16)(va.y >> 16)) - bf2f((u16)(vm.y >> 16))) << 16);
    o.z = (uint32)f2bf(bf2f((u16)(va.z & 0xffff)) - bf2f((u16)(vm.z & 0xffff)))
        | ((uint32)f2bf(bf2f((u16)(va.z >> 16)) - bf2f((u16)(vm.z >> 16))) << 16);
    o.w = (uint32)f2bf(bf2f((u16)(va.w & 0xffff)) - bf2f((u16)(vm.w & 0xffff)))
        | ((uint32)f2bf(bf2f((u16)(va.w >> 16)) - bf2f((u16)(vm.w >> 16))) << 16);
    ((uint4*)h)[(size_t)b * 40 + swz_chunk(c, b)] = o;
}

// pad+cast fp32 -> bf16, swizzled destination
__global__ __launch_bounds__(256) void padcast_k(
    const float* __restrict__ src, int srows, int scols,
    u16* __restrict__ dst, int drows, int dcols)
{
    int idx = blockIdx.x * 256 + threadIdx.x;
    if (idx >= drows * dcols) return;
    int r = idx / dcols, c = idx - r * dcols;
    float v = (r < srows && c < scols) ? src[(size_t)r * scols + c] : 0.f;
    dst[(size_t)r * dcols + swz_elem(c, r)] = f2bf(v);
}

// Wf[900][160] fp32 = W_ih[900][300] @ W_i[300][147] (cols >=147 zero), unswizzled
__global__ __launch_bounds__(256) void wf_k(
    const float* __restrict__ W_ih, const float* __restrict__ W_i, float* __restrict__ Wf)
{
    int idx = blockIdx.x * 256 + threadIdx.x;
    if (idx >= 900 * 160) return;
    int r = idx / 160, c = idx - r * 160;
    float s = 0.f;
    if (c < BOND_FDIM) {
        for (int k = 0; k < HIDDEN; ++k)
            s += W_ih[(size_t)r * HIDDEN + k] * W_i[(size_t)k * BOND_FDIM + c];
    }
    Wf[idx] = s;
}

// W4[4][320][480] bf16 swizzled: r/z: [Wf_g | W_hh_g]; i_n: [Wf_n | 0]; h_n: [0 | W_hh_n]
__global__ __launch_bounds__(256) void prep_W4_k(
    const float* __restrict__ Wf, const float* __restrict__ W_hh, u16* __restrict__ W4)
{
    int idx = blockIdx.x * 256 + threadIdx.x;
    if (idx >= 4 * HP * 480) return;
    int g = idx / (HP * 480); int rem = idx - g * HP * 480;
    int n = rem / 480, k = rem - n * 480;
    float v = 0.f;
    if (n < HIDDEN) {
        if (g <= 1) {
            if (k < KB_PAD) v = Wf[(size_t)(g * HIDDEN + n) * 160 + k];
            else if (k < KB_PAD + HIDDEN) v = W_hh[(size_t)(g * HIDDEN + n) * HIDDEN + (k - KB_PAD)];
        } else if (g == 2) {
            if (k < KB_PAD) v = Wf[(size_t)(2 * HIDDEN + n) * 160 + k];
        } else {
            if (k >= KB_PAD && k < KB_PAD + HIDDEN) v = W_hh[(size_t)(2 * HIDDEN + n) * HIDDEN + (k - KB_PAD)];
        }
    }
    W4[(size_t)(g * HP + n) * 480 + swz_elem(k, n)] = f2bf(v);
}

// bias4[4*320]: r: b_ih_r+b_hh_r; z: b_ih_z+b_hh_z; i_n: b_ih_n; h_n: b_hh_n
__global__ __launch_bounds__(256) void bias4_k(
    const float* __restrict__ b_ih, const float* __restrict__ b_hh, float* __restrict__ b4)
{
    int idx = blockIdx.x * 256 + threadIdx.x;
    if (idx >= 4 * HP) return;
    int g = idx / HP, n = idx - g * HP;
    float v = 0.f;
    if (n < HIDDEN) {
        if (g == 0) v = b_ih[n] + b_hh[n];
        else if (g == 1) v = b_ih[HIDDEN + n] + b_hh[HIDDEN + n];
        else if (g == 2) v = b_ih[2 * HIDDEN + n];
        else v = b_hh[2 * HIDDEN + n];
    }
    b4[idx] = v;
}

// W_o [300][433] -> [320][480] swizzled: k<133 atom part, k in [160,460) hidden part
__global__ __launch_bounds__(256) void padWo_k(const float* __restrict__ src, u16* __restrict__ dst)
{
    int idx = blockIdx.x * 256 + threadIdx.x;
    if (idx >= HP * 480) return;
    int n = idx / 480, k = idx - n * 480;
    float v = 0.f;
    if (n < HIDDEN) {
        if (k < ATOM_FDIM) v = src[(size_t)n * 433 + k];
        else if (k >= KA_PAD && k < KA_PAD + HIDDEN) v = src[(size_t)n * 433 + ATOM_FDIM + (k - KA_PAD)];
    }
    dst[(size_t)n * 480 + swz_elem(k, n)] = f2bf(v);
}

__global__ __launch_bounds__(256) void sentinel_k(float* __restrict__ out, int n)
{
    int i = blockIdx.x * 256 + threadIdx.x;
    if (i < n) out[i] = 31415.0f;
}

extern "C" void kernel_launch(void* const* d_in, const int* in_sizes, int n_in,
                              void* d_out, int out_size, void* d_ws, size_t ws_size,
                              hipStream_t stream)
{
    const float* f_atoms = (const float*)d_in[0];
    const float* f_bonds = (const float*)d_in[1];
    const int*   a2b     = (const int*)d_in[2];
    const int*   b2a     = (const int*)d_in[3];
    const int*   b2revb  = (const int*)d_in[4];
    const float* maskp   = (const float*)d_in[8];
    const float* W_i     = (const float*)d_in[9];
    const float* W_ih    = (const float*)d_in[10];
    const float* W_hh    = (const float*)d_in[11];
    const float* b_ih    = (const float*)d_in[12];
    const float* b_hh    = (const float*)d_in[13];
    const float* W_o_w   = (const float*)d_in[14];
    const float* W_o_b   = (const float*)d_in[15];
    float* out = (float*)d_out;

    char* ws = (char*)d_ws;
    size_t off = 0;
    auto alloc = [&](size_t bytes) -> char* {
        char* p = ws + off;
        off += (bytes + 255) & ~(size_t)255;
        return p;
    };
    u16*   Wi_p   = (u16*)alloc((size_t)HP * KB_PAD * 2);
    u16*   W4     = (u16*)alloc((size_t)4 * HP * 480 * 2);
    u16*   Wo_p   = (u16*)alloc((size_t)HP * 480 * 2);
    float* bias4  = (float*)alloc((size_t)4 * HP * 4);
    float* Wf     = (float*)alloc((size_t)900 * 160 * 4);
    u16*   fa_p   = (u16*)alloc((size_t)NA_PAD * KA_PAD * 2);
    u16*   fb_p   = (u16*)alloc((size_t)NB_PAD * KB_PAD * 2);
    u16*   message= (u16*)alloc((size_t)NB_PAD * HP * 2);
    u16*   hbuf   = (u16*)alloc((size_t)NB_PAD * HP * 2);
    u16*   amsg   = (u16*)alloc((size_t)NA_PAD * HP * 2);

    if (off > ws_size) {
        sentinel_k<<<(out_size + 255) / 256, 256, 0, stream>>>(out, out_size);
        return;
    }

    // --- prep (all bf16 buffers written pre-swizzled) ---
    padcast_k<<<(HP * KB_PAD + 255) / 256, 256, 0, stream>>>(W_i, HIDDEN, BOND_FDIM, Wi_p, HP, KB_PAD);
    padcast_k<<<(NB_PAD * KB_PAD + 255) / 256, 256, 0, stream>>>(f_bonds, N_BONDS, BOND_FDIM, fb_p, NB_PAD, KB_PAD);
    padcast_k<<<(NA_PAD * KA_PAD + 255) / 256, 256, 0, stream>>>(f_atoms, N_ATOMS, ATOM_FDIM, fa_p, NA_PAD, KA_PAD);
    wf_k<<<(900 * 160 + 255) / 256, 256, 0, stream>>>(W_ih, W_i, Wf);
    prep_W4_k<<<(4 * HP * 480 + 255) / 256, 256, 0, stream>>>(Wf, W_hh, W4);
    bias4_k<<<(4 * HP + 255) / 256, 256, 0, stream>>>(b_ih, b_hh, bias4);
    padWo_k<<<(HP * 480 + 255) / 256, 256, 0, stream>>>(W_o_w, Wo_p);

    dim3 blk(256);
    dim3 gB(NB_PAD / 128, 5);
    // message = inp = f_bonds @ W_i.T
    gemm_k<1, 0><<<gB, blk, 0, stream>>>(fb_p, KB_PAD * 2, nullptr, 0, 1 << 30, Wi_p, KB_PAD * 2,
                                         5, N_BONDS, message, HP,
                                         nullptr, nullptr, nullptr);
    for (int d = 0; d < DEPTH - 1; ++d) {
        gather_sum_k<<<(N_ATOMS * 40 + 255) / 256, 256, 0, stream>>>(message, a2b, amsg);
        build_h_k<<<(N_BONDS * 40 + 255) / 256, 256, 0, stream>>>(amsg, message, b2a, b2revb, hbuf);
        gemm_gru_k<<<gB, blk, 0, stream>>>(fb_p, hbuf, W4, bias4, hbuf, message);
    }
    gather_sum_k<<<(N_ATOMS * 40 + 255) / 256, 256, 0, stream>>>(message, a2b, amsg);
    dim3 gO(NA_PAD / 128, 5);
    gemm_k<1, 2><<<gO, blk, 0, stream>>>(fa_p, KA_PAD * 2, amsg, HP * 2, 5, Wo_p, 480 * 2,
                                         15, N_ATOMS, nullptr, 0,
                                         W_o_b, out, maskp);
}

// Round 6
// 1477.892 us; speedup vs baseline: 1.0310x; 1.0073x over previous
//
#include <hip/hip_runtime.h>
#include <hip/hip_bf16.h>
#include <stdint.h>

#define N_ATOMS 40000
#define N_BONDS 90000
#define MAX_NB 6
#define ATOM_FDIM 133
#define BOND_FDIM 147
#define HIDDEN 300
#define DEPTH 6

// padded dims
#define KB_PAD 160
#define KA_PAD 160
#define HP 320
#define NB_PAD 90112
#define NA_PAD 40064
#define AK 512          // A' row: [fb 0..160 | zeros 160..192 | h 192..512)

typedef unsigned short u16;
typedef unsigned int uint32;

typedef __bf16 bf16x8 __attribute__((ext_vector_type(8)));
typedef float f32x4 __attribute__((ext_vector_type(4)));
typedef uint32 u32x4 __attribute__((ext_vector_type(4)));

#define GLOBAL_AS __attribute__((address_space(1)))
#define LDS_AS __attribute__((address_space(3)))

__device__ __forceinline__ void async_copy16(const void* g, void* l) {
    __builtin_amdgcn_global_load_lds((GLOBAL_AS void*)(void*)g,
                                     (LDS_AS void*)l, 16, 0, 0);
}
__device__ __forceinline__ void raw_barrier() {
    asm volatile("s_barrier" ::: "memory");
}
#define WAITCNT_VM(N) __builtin_amdgcn_s_waitcnt(0xF70 | (N))

__device__ __forceinline__ uint32 lds_addr(const void* p) {
    return (uint32)(size_t)(LDS_AS const char*)(const char*)p;
}
// opaque LDS read: compiler sees no LDS hazard -> no forced vmcnt(0) drain
__device__ __forceinline__ u32x4 ldsr(uint32 addr) {
    u32x4 v;
    asm volatile("ds_read_b128 %0, %1" : "=v"(v) : "v"(addr));
    return v;
}
// data-carrying lgkm fence: MFMAs consuming these values cannot be hoisted above it
#define LGKM_FENCE14(a0,a1,b00,b01,b02,b03,b10,b11,b12,b13,b20,b21,b22,b23) \
    asm volatile("s_waitcnt lgkmcnt(0)" \
        : "+v"(a0),"+v"(a1),"+v"(b00),"+v"(b01),"+v"(b02),"+v"(b03), \
          "+v"(b10),"+v"(b11),"+v"(b12),"+v"(b13), \
          "+v"(b20),"+v"(b21),"+v"(b22),"+v"(b23))

__device__ __forceinline__ bf16x8 asbf(u32x4 v) { return __builtin_bit_cast(bf16x8, v); }

__device__ __forceinline__ float bf2f(u16 s) {
    union { uint32 u; float f; } v; v.u = ((uint32)s) << 16; return v.f;
}
__device__ __forceinline__ u16 f2bf(float f) {
    union { float f; uint32 u; } v; v.f = f;
    uint32 r = v.u + 0x7fffu + ((v.u >> 16) & 1u);
    return (u16)(r >> 16);
}
__device__ __forceinline__ float sigm(float x) { return 1.f / (1.f + __expf(-x)); }
__device__ __forceinline__ float tanh_s(float x) {
    float e = __expf(-2.f * fabsf(x));
    float t = (1.f - e) / (1.f + e);
    return x >= 0.f ? t : -t;
}

// XOR chunk swizzle (R3: verified SQ_LDS_BANK_CONFLICT == 0)
__device__ __forceinline__ int swz_chunk(int c, int row) {
    return (c & ~3) | ((c & 3) ^ ((row >> 1) & 3));
}
__device__ __forceinline__ int swz_elem(int e, int row) {
    return (e & ~31) | (((((e >> 3) & 3)) ^ ((row >> 1) & 3)) << 3) | (e & 7);
}

// ---------------------------------------------------------------------------
// Generic GEMM (R5 structure): first GEMM (inp) and final output GEMM.
// ---------------------------------------------------------------------------
template<int NG, int EPI>
__global__ __launch_bounds__(256, 2) void gemm_k(
    const u16* __restrict__ A, int ldaB,
    const u16* __restrict__ A2, int lda2B, int ksplit,
    const u16* __restrict__ Bw, int ldbB,
    int ksteps, int M,
    u16* __restrict__ C1, int ldc,
    const float* __restrict__ bias,
    float* __restrict__ outp, const float* __restrict__ omask)
{
    __shared__ __align__(16) u16 lsA[2 * 128 * 32];
    __shared__ __align__(16) u16 lsB[2 * NG * 64 * 32];

    const int tid = threadIdx.x;
    const int wv = tid >> 6, ln = tid & 63;
    const int m0 = blockIdx.x * 128;
    const int n0 = blockIdx.y * 64;
    const int lhalf = ln >> 4, l16 = ln & 15;
    const int aoff = ((lhalf ^ ((l16 >> 1) & 3))) * 8;

    f32x4 acc[NG][2][4];
#pragma unroll
    for (int g = 0; g < NG; ++g)
#pragma unroll
        for (int r = 0; r < 2; ++r)
#pragma unroll
            for (int c = 0; c < 4; ++c) { f32x4 z = {0.f, 0.f, 0.f, 0.f}; acc[g][r][c] = z; }

    auto stage = [&](int ks, int buf) {
        const char* Abase; int ldA;
        if (ks < ksplit) { Abase = (const char*)A + (size_t)ks * 64; ldA = ldaB; }
        else             { Abase = (const char*)A2 + (size_t)(ks - ksplit) * 64; ldA = lda2B; }
#pragma unroll
        for (int c = 0; c < 2; ++c) {
            int chunk = wv * 2 + c;
            int idx = chunk * 64 + ln;
            int row = idx >> 2, kb = (idx & 3) * 16;
            async_copy16(Abase + (size_t)(m0 + row) * ldA + kb, &lsA[buf * 4096 + chunk * 512]);
        }
        int idx = wv * 64 + ln;
        int n = idx >> 2, kb = (idx & 3) * 16;
#pragma unroll
        for (int g = 0; g < NG; ++g)
            async_copy16((const char*)Bw + (size_t)(g * 320 + n0 + n) * ldbB + (size_t)ks * 64 + kb,
                         &lsB[buf * (NG * 2048) + g * 2048 + wv * 512]);
    };

    stage(0, 0);
    for (int ks = 0; ks < ksteps; ++ks) {
        int buf = ks & 1;
        if (ks + 1 < ksteps) {
            stage(ks + 1, buf ^ 1);
            WAITCNT_VM(2 + NG);
        } else {
            WAITCNT_VM(0);
        }
        raw_barrier();

        bf16x8 af[2];
#pragma unroll
        for (int r = 0; r < 2; ++r)
            af[r] = *(const bf16x8*)&lsA[buf * 4096 + (wv * 32 + r * 16 + l16) * 32 + aoff];
#pragma unroll
        for (int g = 0; g < NG; ++g) {
#pragma unroll
            for (int c = 0; c < 4; ++c) {
                bf16x8 bfv = *(const bf16x8*)&lsB[buf * (NG * 2048) + g * 2048 + (c * 16 + l16) * 32 + aoff];
#pragma unroll
                for (int r = 0; r < 2; ++r)
                    acc[g][r][c] = __builtin_amdgcn_mfma_f32_16x16x32_bf16(af[r], bfv, acc[g][r][c], 0, 0, 0);
            }
        }
        raw_barrier();
    }

    const int mrow_base = m0 + wv * 32;
#pragma unroll
    for (int r = 0; r < 2; ++r) {
#pragma unroll
        for (int c = 0; c < 4; ++c) {
            int nn_ = n0 + c * 16 + l16;
#pragma unroll
            for (int i = 0; i < 4; ++i) {
                int m = mrow_base + r * 16 + lhalf * 4 + i;
                if (m >= M) continue;
                if constexpr (EPI == 0) {
                    int pc = swz_elem(nn_, m);
#pragma unroll
                    for (int g = 0; g < NG; ++g) {
                        float v = acc[g][r][c][i];
                        if (bias != nullptr && nn_ < HIDDEN) v += bias[g * HIDDEN + nn_];
                        C1[(size_t)m * ldc + g * 320 + pc] = f2bf(v);
                    }
                } else { // EPI == 2
                    if (nn_ < HIDDEN) {
                        float v = acc[0][r][c][i] + (bias ? bias[nn_] : 0.f);
                        v = fmaxf(v, 0.f);
                        if (omask) v *= omask[m];
                        outp[(size_t)m * HIDDEN + nn_] = v;
                    }
                }
            }
        }
    }
}

// ---------------------------------------------------------------------------
// Fused GRU GEMM, BK=64, 8 rounds, asm ds_read + raw barriers + vmcnt pipeline.
// A' [NB_PAD][512]: [fb 160 | 0 x32 | h 320], one A source, no phases.
// Wc [3][320][512]: slot0=r, slot1=z, slot2 = i_n (K<192) / h_n (K>=192).
// Rounds 0..2 accumulate slot2 into acc2 (i_n), rounds 3..7 into acc3 (h_n).
// ---------------------------------------------------------------------------
__global__ __launch_bounds__(256, 2) void gemm_gru_k(
    const u16* __restrict__ Ap,
    const u16* __restrict__ Wc,
    const float* __restrict__ bias,   // [4*320]: r, z, i_n, h_n
    u16* __restrict__ msg_out)
{
    __shared__ __align__(16) u16 lsA[2 * 128 * 64];     // 32 KB
    __shared__ __align__(16) u16 lsB[2 * 3 * 64 * 64];  // 48 KB

    const int tid = threadIdx.x;
    const int wv = tid >> 6, ln = tid & 63;
    const int m0 = blockIdx.x * 128;
    const int n0 = blockIdx.y * 64;
    const int lhalf = ln >> 4, l16 = ln & 15;
    const int swzB = ((lhalf ^ ((l16 >> 1) & 3))) * 16;   // byte swizzle within 64B group

    const uint32 aBase = lds_addr(lsA) + (uint32)((wv * 32 + l16) * 128 + swzB);
    const uint32 bBase = lds_addr(lsB) + (uint32)(l16 * 128 + swzB);

    f32x4 acc0[2][4], acc1[2][4], acc2[2][4], acc3[2][4];
#pragma unroll
    for (int r = 0; r < 2; ++r)
#pragma unroll
        for (int c = 0; c < 4; ++c) {
            f32x4 z = {0.f, 0.f, 0.f, 0.f};
            acc0[r][c] = z; acc1[r][c] = z; acc2[r][c] = z; acc3[r][c] = z;
        }

    auto stage = [&](int ks, int buf) {
        // A tile: 128 rows x 128B, 16 chunks of 1KB, 4 per wave
#pragma unroll
        for (int c2 = 0; c2 < 4; ++c2) {
            int ch = wv * 4 + c2;
            int gi = ch * 64 + ln;
            int row = gi >> 3, k16 = gi & 7;
            async_copy16((const char*)Ap + (size_t)(m0 + row) * 1024 + (size_t)ks * 128 + k16 * 16,
                         (u16*)lsA + buf * 8192 + ch * 512);
        }
        // B tiles: 3 slots x 64 rows x 128B = 24 chunks, 6 per wave
#pragma unroll
        for (int c2 = 0; c2 < 6; ++c2) {
            int bc = wv * 6 + c2;
            int s = bc >> 3, ch = bc & 7;
            int gi = ch * 64 + ln;
            int n = gi >> 3, k16 = gi & 7;
            async_copy16((const char*)Wc + (size_t)(s * 320 + n0 + n) * 1024 + (size_t)ks * 128 + k16 * 16,
                         (u16*)lsB + buf * 12288 + s * 4096 + ch * 512);
        }
    };

    stage(0, 0);
#pragma unroll
    for (int ks = 0; ks < 8; ++ks) {
        const int buf = ks & 1;
        if (ks < 7) {
            stage(ks + 1, buf ^ 1);
            WAITCNT_VM(10);   // my 10 loads for round ks done; prefetch stays in flight
        } else {
            WAITCNT_VM(0);
        }
        raw_barrier();

#pragma unroll
        for (int kh = 0; kh < 2; ++kh) {
            const uint32 ab = aBase + (uint32)(buf * 16384 + kh * 64);
            const uint32 bb = bBase + (uint32)(buf * 24576 + kh * 64);
            u32x4 ra0 = ldsr(ab);
            u32x4 ra1 = ldsr(ab + 2048);
            u32x4 rb0[4], rb1[4], rb2[4];
#pragma unroll
            for (int c = 0; c < 4; ++c) rb0[c] = ldsr(bb + (uint32)(c * 2048));
#pragma unroll
            for (int c = 0; c < 4; ++c) rb1[c] = ldsr(bb + (uint32)(8192 + c * 2048));
#pragma unroll
            for (int c = 0; c < 4; ++c) rb2[c] = ldsr(bb + (uint32)(16384 + c * 2048));
            LGKM_FENCE14(ra0, ra1, rb0[0], rb0[1], rb0[2], rb0[3],
                         rb1[0], rb1[1], rb1[2], rb1[3],
                         rb2[0], rb2[1], rb2[2], rb2[3]);
            bf16x8 a0 = asbf(ra0), a1 = asbf(ra1);
#pragma unroll
            for (int c = 0; c < 4; ++c) {
                bf16x8 b0 = asbf(rb0[c]), b1 = asbf(rb1[c]), b2 = asbf(rb2[c]);
                acc0[0][c] = __builtin_amdgcn_mfma_f32_16x16x32_bf16(a0, b0, acc0[0][c], 0, 0, 0);
                acc0[1][c] = __builtin_amdgcn_mfma_f32_16x16x32_bf16(a1, b0, acc0[1][c], 0, 0, 0);
                acc1[0][c] = __builtin_amdgcn_mfma_f32_16x16x32_bf16(a0, b1, acc1[0][c], 0, 0, 0);
                acc1[1][c] = __builtin_amdgcn_mfma_f32_16x16x32_bf16(a1, b1, acc1[1][c], 0, 0, 0);
                if (ks < 3) {
                    acc2[0][c] = __builtin_amdgcn_mfma_f32_16x16x32_bf16(a0, b2, acc2[0][c], 0, 0, 0);
                    acc2[1][c] = __builtin_amdgcn_mfma_f32_16x16x32_bf16(a1, b2, acc2[1][c], 0, 0, 0);
                } else {
                    acc3[0][c] = __builtin_amdgcn_mfma_f32_16x16x32_bf16(a0, b2, acc3[0][c], 0, 0, 0);
                    acc3[1][c] = __builtin_amdgcn_mfma_f32_16x16x32_bf16(a1, b2, acc3[1][c], 0, 0, 0);
                }
            }
        }
        raw_barrier();
    }

    const int mrow_base = m0 + wv * 32;
#pragma unroll
    for (int r = 0; r < 2; ++r) {
#pragma unroll
        for (int c = 0; c < 4; ++c) {
            int nn_ = n0 + c * 16 + l16;
#pragma unroll
            for (int i = 0; i < 4; ++i) {
                int m = mrow_base + r * 16 + lhalf * 4 + i;
                if (m >= N_BONDS) continue;
                float rl  = ((r == 0) ? acc0[0][c][i] : acc0[1][c][i]) + bias[nn_];
                float zl  = ((r == 0) ? acc1[0][c][i] : acc1[1][c][i]) + bias[320 + nn_];
                float in_ = ((r == 0) ? acc2[0][c][i] : acc2[1][c][i]) + bias[640 + nn_];
                float hn_ = ((r == 0) ? acc3[0][c][i] : acc3[1][c][i]) + bias[960 + nn_];
                float hv = bf2f(Ap[(size_t)m * AK + swz_elem(192 + nn_, m)]);
                float rr = sigm(rl);
                float zz = sigm(zl);
                float nv = tanh_s(in_ + rr * hn_);
                float msg = (1.f - zz) * nv + zz * hv;
                if (m == 0) msg = 0.f;
                msg_out[(size_t)m * HP + swz_elem(nn_, m)] = f2bf(msg);
            }
        }
    }
}

// a_message[a,:] = sum_j message[a2b[a,j],:]
__global__ __launch_bounds__(256) void gather_sum_k(
    const u16* __restrict__ msg, const int* __restrict__ a2b, u16* __restrict__ amsg)
{
    int u = blockIdx.x * 256 + threadIdx.x;
    if (u >= N_ATOMS * 40) return;
    int a = u / 40, c = u - a * 40;
    const uint4* mp = (const uint4*)msg;
    float s[8];
#pragma unroll
    for (int t = 0; t < 8; ++t) s[t] = 0.f;
#pragma unroll
    for (int j = 0; j < MAX_NB; ++j) {
        int b = a2b[a * MAX_NB + j];
        uint4 v = mp[(size_t)b * 40 + swz_chunk(c, b)];
        s[0] += bf2f((u16)(v.x & 0xffff)); s[1] += bf2f((u16)(v.x >> 16));
        s[2] += bf2f((u16)(v.y & 0xffff)); s[3] += bf2f((u16)(v.y >> 16));
        s[4] += bf2f((u16)(v.z & 0xffff)); s[5] += bf2f((u16)(v.z >> 16));
        s[6] += bf2f((u16)(v.w & 0xffff)); s[7] += bf2f((u16)(v.w >> 16));
    }
    uint4 o;
    o.x = (uint32)f2bf(s[0]) | ((uint32)f2bf(s[1]) << 16);
    o.y = (uint32)f2bf(s[2]) | ((uint32)f2bf(s[3]) << 16);
    o.z = (uint32)f2bf(s[4]) | ((uint32)f2bf(s[5]) << 16);
    o.w = (uint32)f2bf(s[6]) | ((uint32)f2bf(s[7]) << 16);
    ((uint4*)amsg)[(size_t)a * 40 + swz_chunk(c, a)] = o;
}

// h part of A': A'[b, 192+..511] = amsg[b2a[b],:] - msg[b2revb[b],:]
__global__ __launch_bounds__(256) void build_h_k(
    const u16* __restrict__ amsg, const u16* __restrict__ msg,
    const int* __restrict__ b2a, const int* __restrict__ b2revb, u16* __restrict__ Ap)
{
    int u = blockIdx.x * 256 + threadIdx.x;
    if (u >= N_BONDS * 40) return;
    int b = u / 40, c = u - b * 40;
    int ra = b2a[b], rm = b2revb[b];
    uint4 va = ((const uint4*)amsg)[(size_t)ra * 40 + swz_chunk(c, ra)];
    uint4 vm = ((const uint4*)msg)[(size_t)rm * 40 + swz_chunk(c, rm)];
    uint4 o;
    o.x = (uint32)f2bf(bf2f((u16)(va.x & 0xffff)) - bf2f((u16)(vm.x & 0xffff)))
        | ((uint32)f2bf(bf2f((u16)(va.x >> 16)) - bf2f((u16)(vm.x >> 16))) << 16);
    o.y = (uint32)f2bf(bf2f((u16)(va.y & 0xffff)) - bf2f((u16)(vm.y & 0xffff)))
        | ((uint32)f2bf(bf2f((u16)(va.y >> 16)) - bf2f((u16)(vm.y >> 16))) << 16);
    o.z = (uint32)f2bf(bf2f((u16)(va.z & 0xffff)) - bf2f((u16)(vm.z & 0xffff)))
        | ((uint32)f2bf(bf2f((u16)(va.z >> 16)) - bf2f((u16)(vm.z >> 16))) << 16);
    o.w = (uint32)f2bf(bf2f((u16)(va.w & 0xffff)) - bf2f((u16)(vm.w & 0xffff)))
        | ((uint32)f2bf(bf2f((u16)(va.w >> 16)) - bf2f((u16)(vm.w >> 16))) << 16);
    // h chunk c maps to A' 16B-chunk 24+c (row = 64 chunks of 16B)
    ((uint4*)Ap)[(size_t)b * 64 + swz_chunk(24 + c, b)] = o;
}

// generic pad+cast fp32 -> bf16 (swizzled rows)
__global__ __launch_bounds__(256) void padcast_k(
    const float* __restrict__ src, int srows, int scols,
    u16* __restrict__ dst, int drows, int dcols)
{
    int idx = blockIdx.x * 256 + threadIdx.x;
    if (idx >= drows * dcols) return;
    int r = idx / dcols, c = idx - r * dcols;
    float v = (r < srows && c < scols) ? src[(size_t)r * scols + c] : 0.f;
    dst[(size_t)r * dcols + swz_elem(c, r)] = f2bf(v);
}

// fb part of A': cols [0,192) = [f_bonds 147 | zeros]
__global__ __launch_bounds__(256) void padcastA_k(
    const float* __restrict__ fb, u16* __restrict__ Ap)
{
    int idx = blockIdx.x * 256 + threadIdx.x;
    if (idx >= NB_PAD * 192) return;
    int r = idx / 192, c = idx - r * 192;
    float v = (r < N_BONDS && c < BOND_FDIM) ? fb[(size_t)r * BOND_FDIM + c] : 0.f;
    Ap[(size_t)r * AK + swz_elem(c, r)] = f2bf(v);
}

// Wf[900][160] fp32 = W_ih[900][300] @ W_i[300][147]
__global__ __launch_bounds__(256) void wf_k(
    const float* __restrict__ W_ih, const float* __restrict__ W_i, float* __restrict__ Wf)
{
    int idx = blockIdx.x * 256 + threadIdx.x;
    if (idx >= 900 * 160) return;
    int r = idx / 160, c = idx - r * 160;
    float s = 0.f;
    if (c < BOND_FDIM) {
        for (int k = 0; k < HIDDEN; ++k)
            s += W_ih[(size_t)r * HIDDEN + k] * W_i[(size_t)k * BOND_FDIM + c];
    }
    Wf[idx] = s;
}

// Wc[3][320][512]: slot0=r, slot1=z: [Wf_g |0| Whh_g |0]; slot2: [Wf_n |0| Whh_n |0]
__global__ __launch_bounds__(256) void prep_Wc_k(
    const float* __restrict__ Wf, const float* __restrict__ W_hh, u16* __restrict__ Wc)
{
    int idx = blockIdx.x * 256 + threadIdx.x;
    if (idx >= 3 * HP * AK) return;
    int s = idx / (HP * AK); int rem = idx - s * HP * AK;
    int n = rem / AK, k = rem - n * AK;
    int gf = (s == 2) ? 2 : s;      // Wf gate index
    int gh = (s == 2) ? 2 : s;      // W_hh gate index
    float v = 0.f;
    if (n < HIDDEN) {
        if (k < 160) v = Wf[(size_t)(gf * HIDDEN + n) * 160 + k];
        else if (k >= 192 && k < 192 + HIDDEN) v = W_hh[(size_t)(gh * HIDDEN + n) * HIDDEN + (k - 192)];
    }
    Wc[(size_t)(s * HP + n) * AK + swz_elem(k, n)] = f2bf(v);
}

// bias4[4*320]: r: b_ih_r+b_hh_r; z: b_ih_z+b_hh_z; i_n: b_ih_n; h_n: b_hh_n
__global__ __launch_bounds__(256) void bias4_k(
    const float* __restrict__ b_ih, const float* __restrict__ b_hh, float* __restrict__ b4)
{
    int idx = blockIdx.x * 256 + threadIdx.x;
    if (idx >= 4 * HP) return;
    int g = idx / HP, n = idx - g * HP;
    float v = 0.f;
    if (n < HIDDEN) {
        if (g == 0) v = b_ih[n] + b_hh[n];
        else if (g == 1) v = b_ih[HIDDEN + n] + b_hh[HIDDEN + n];
        else if (g == 2) v = b_ih[2 * HIDDEN + n];
        else v = b_hh[2 * HIDDEN + n];
    }
    b4[idx] = v;
}

// W_o [300][433] -> [320][480] swizzled
__global__ __launch_bounds__(256) void padWo_k(const float* __restrict__ src, u16* __restrict__ dst)
{
    int idx = blockIdx.x * 256 + threadIdx.x;
    if (idx >= HP * 480) return;
    int n = idx / 480, k = idx - n * 480;
    float v = 0.f;
    if (n < HIDDEN) {
        if (k < ATOM_FDIM) v = src[(size_t)n * 433 + k];
        else if (k >= KA_PAD && k < KA_PAD + HIDDEN) v = src[(size_t)n * 433 + ATOM_FDIM + (k - KA_PAD)];
    }
    dst[(size_t)n * 480 + swz_elem(k, n)] = f2bf(v);
}

__global__ __launch_bounds__(256) void sentinel_k(float* __restrict__ out, int n)
{
    int i = blockIdx.x * 256 + threadIdx.x;
    if (i < n) out[i] = 31415.0f;
}

extern "C" void kernel_launch(void* const* d_in, const int* in_sizes, int n_in,
                              void* d_out, int out_size, void* d_ws, size_t ws_size,
                              hipStream_t stream)
{
    const float* f_atoms = (const float*)d_in[0];
    const float* f_bonds = (const float*)d_in[1];
    const int*   a2b     = (const int*)d_in[2];
    const int*   b2a     = (const int*)d_in[3];
    const int*   b2revb  = (const int*)d_in[4];
    const float* maskp   = (const float*)d_in[8];
    const float* W_i     = (const float*)d_in[9];
    const float* W_ih    = (const float*)d_in[10];
    const float* W_hh    = (const float*)d_in[11];
    const float* b_ih    = (const float*)d_in[12];
    const float* b_hh    = (const float*)d_in[13];
    const float* W_o_w   = (const float*)d_in[14];
    const float* W_o_b   = (const float*)d_in[15];
    float* out = (float*)d_out;

    char* ws = (char*)d_ws;
    size_t off = 0;
    auto alloc = [&](size_t bytes) -> char* {
        char* p = ws + off;
        off += (bytes + 255) & ~(size_t)255;
        return p;
    };
    u16*   Wi_p   = (u16*)alloc((size_t)HP * KB_PAD * 2);       // [320][160]
    u16*   Wc     = (u16*)alloc((size_t)3 * HP * AK * 2);       // [3][320][512]
    u16*   Wo_p   = (u16*)alloc((size_t)HP * 480 * 2);
    float* bias4  = (float*)alloc((size_t)4 * HP * 4);
    float* Wf     = (float*)alloc((size_t)900 * 160 * 4);
    u16*   fa_p   = (u16*)alloc((size_t)NA_PAD * KA_PAD * 2);
    u16*   Aprime = (u16*)alloc((size_t)NB_PAD * AK * 2);       // 92.3 MB
    u16*   message= (u16*)alloc((size_t)NB_PAD * HP * 2);       // 57.7 MB
    u16*   amsg   = (u16*)alloc((size_t)NA_PAD * HP * 2);       // 25.6 MB

    if (off > ws_size) {
        sentinel_k<<<(out_size + 255) / 256, 256, 0, stream>>>(out, out_size);
        return;
    }

    // --- prep ---
    padcast_k<<<(HP * KB_PAD + 255) / 256, 256, 0, stream>>>(W_i, HIDDEN, BOND_FDIM, Wi_p, HP, KB_PAD);
    padcastA_k<<<(NB_PAD * 192 + 255) / 256, 256, 0, stream>>>(f_bonds, Aprime);
    padcast_k<<<(NA_PAD * KA_PAD + 255) / 256, 256, 0, stream>>>(f_atoms, N_ATOMS, ATOM_FDIM, fa_p, NA_PAD, KA_PAD);
    wf_k<<<(900 * 160 + 255) / 256, 256, 0, stream>>>(W_ih, W_i, Wf);
    prep_Wc_k<<<(3 * HP * AK + 255) / 256, 256, 0, stream>>>(Wf, W_hh, Wc);
    bias4_k<<<(4 * HP + 255) / 256, 256, 0, stream>>>(b_ih, b_hh, bias4);
    padWo_k<<<(HP * 480 + 255) / 256, 256, 0, stream>>>(W_o_w, Wo_p);

    dim3 blk(256);
    dim3 gB(NB_PAD / 128, 5);
    // message = inp = f_bonds @ W_i.T   (A = fb region of A', lda = 1024B)
    gemm_k<1, 0><<<gB, blk, 0, stream>>>(Aprime, AK * 2, nullptr, 0, 1 << 30, Wi_p, KB_PAD * 2,
                                         5, N_BONDS, message, HP,
                                         nullptr, nullptr, nullptr);
    for (int d = 0; d < DEPTH - 1; ++d) {
        gather_sum_k<<<(N_ATOMS * 40 + 255) / 256, 256, 0, stream>>>(message, a2b, amsg);
        build_h_k<<<(N_BONDS * 40 + 255) / 256, 256, 0, stream>>>(amsg, message, b2a, b2revb, Aprime);
        gemm_gru_k<<<gB, blk, 0, stream>>>(Aprime, Wc, bias4, message);
    }
    gather_sum_k<<<(N_ATOMS * 40 + 255) / 256, 256, 0, stream>>>(message, a2b, amsg);
    dim3 gO(NA_PAD / 128, 5);
    gemm_k<1, 2><<<gO, blk, 0, stream>>>(fa_p, KA_PAD * 2, amsg, HP * 2, 5, Wo_p, 480 * 2,
                                         15, N_ATOMS, nullptr, 0,
                                         W_o_b, out, maskp);
}